// Round 7
// baseline (1680.002 us; speedup 1.0000x reference)
//
#include <hip/hip_runtime.h>

#define HW 4096

__device__ __forceinline__ float hswish(float x) {
  float r = fminf(fmaxf(x + 3.0f, 0.0f), 6.0f);
  return x * r * (1.0f / 6.0f);
}

__device__ __forceinline__ void atomic_add_f32(float* p, float v) {
  __hip_atomic_fetch_add(p, v, __ATOMIC_RELAXED, __HIP_MEMORY_SCOPE_AGENT);
}

__global__ __launch_bounds__(256) void zero_buf4(float4* __restrict__ p, int n4) {
  int i = blockIdx.x * 256 + threadIdx.x;
  if (i < n4) p[i] = make_float4(0.f, 0.f, 0.f, 0.f);
}

// Transpose W[CO][K] -> WT[K][CO]. CO, K powers of two. Coalesced writes.
__global__ __launch_bounds__(256) void transpose_w(
    const float* __restrict__ in, float* __restrict__ out,
    int K, int comask, int coshift)
{
  int i = blockIdx.x * 256 + threadIdx.x;   // i = k*CO + co
  int co = i & comask;
  int k  = i >> coshift;
  out[i] = in[(size_t)co * K + k];
}

// Scalar-broadcast 1x1-conv GEMM. 256 threads = 256 spatial positions (one per
// lane); each thread accumulates 32 consecutive co. W operand comes from WT[K][CO]
// via block-uniform indices -> SGPR s_load broadcast (zero LDS traffic for W).
// A staged in LDS [32][256], one conflict-free ds_read_b32 per 32 FMAs.
// Grid dim3(16, CO/32, 4). epi: 0 none, 1 g*x+b, 2 hswish(g*x+b), 3 hswish(x+b)
__global__ __launch_bounds__(256) void gemm1x1_sw(
    const float* __restrict__ in0, const float* __restrict__ in1,
    const float* __restrict__ WT, float* __restrict__ out,
    const float* __restrict__ scale, const float* __restrict__ bias,
    int K, int k0, int CO, int epi)
{
  __shared__ float At[32][256];   // 32 KB
  const int p0  = blockIdx.x * 256;
  const int co0 = blockIdx.y * 32;
  const int b   = blockIdx.z;
  const int t   = threadIdx.x;
  const int k1  = K - k0;

  float acc[32] = {};
  float4 st[8];

  // prologue: stage K-tile 0 into regs
  #pragma unroll
  for (int j = 0; j < 8; ++j) {
    int id = j * 256 + t;
    int r = id >> 6, c = (id & 63) << 2;
    const float* src = (r < k0)
        ? in0 + ((size_t)b * k0 + r) * HW
        : in1 + ((size_t)b * k1 + (r - k0)) * HW;
    st[j] = *(const float4*)(src + p0 + c);
  }

  for (int kt = 0; kt < K; kt += 32) {
    #pragma unroll
    for (int j = 0; j < 8; ++j) {
      int id = j * 256 + t;
      int r = id >> 6, c = (id & 63) << 2;
      *(float4*)&At[r][c] = st[j];
    }
    __syncthreads();
    if (kt + 32 < K) {
      #pragma unroll
      for (int j = 0; j < 8; ++j) {
        int id = j * 256 + t;
        int r = kt + 32 + (id >> 6), c = (id & 63) << 2;
        const float* src = (r < k0)
            ? in0 + ((size_t)b * k0 + r) * HW
            : in1 + ((size_t)b * k1 + (r - k0)) * HW;
        st[j] = *(const float4*)(src + p0 + c);
      }
    }
    const float* wp = WT + (size_t)kt * CO + co0;   // block-uniform
    #pragma unroll 4
    for (int k = 0; k < 32; ++k) {
      float a = At[k][t];
      const float* wr = wp + (size_t)k * CO;        // block-uniform row
      #pragma unroll
      for (int i = 0; i < 32; ++i)
        acc[i] = fmaf(wr[i], a, acc[i]);            // SGPR * VGPR fma
    }
    __syncthreads();
  }

  #pragma unroll 4
  for (int i = 0; i < 32; ++i) {
    int co = co0 + i;
    float v = acc[i];
    if (epi == 1)      v = v * scale[co] + bias[co];
    else if (epi == 2) v = hswish(v * scale[co] + bias[co]);
    else if (epi == 3) v = hswish(v + bias[co]);
    out[((size_t)b * CO + co) * HW + p0 + t] = v;
  }
}

// LDS-tiled depthwise 3x3, pad 1, branch-free inner loop. One block per (b,c).
// epi: 2 hswish(scale*x+bias), 3 hswish(x+bias)
__global__ __launch_bounds__(256) void dwconv3(
    const float* __restrict__ in, const float* __restrict__ w,
    float* __restrict__ out, const float* __restrict__ scale,
    const float* __restrict__ bias, int Cmask, int epi)
{
  __shared__ float tl[66 * 66];
  const int bc = blockIdx.x;
  const int c  = bc & Cmask;
  const float* src = in + (size_t)bc * HW;
  const int t = threadIdx.x;
  for (int i = t; i < 66 * 66; i += 256) {
    int r = i / 66, cc = i - r * 66;
    int gy = r - 1, gx = cc - 1;
    float v = 0.0f;
    if (gy >= 0 && gy < 64 && gx >= 0 && gx < 64) v = src[(gy << 6) + gx];
    tl[i] = v;
  }
  const float* wp = w + c * 9;
  float w00 = wp[0], w01 = wp[1], w02 = wp[2];
  float w10 = wp[3], w11 = wp[4], w12 = wp[5];
  float w20 = wp[6], w21 = wp[7], w22 = wp[8];
  float g = (epi == 2) ? scale[c] : 1.0f;
  float bb = bias[c];
  __syncthreads();
  float* op = out + (size_t)bc * HW;
  #pragma unroll 4
  for (int j = 0; j < 16; ++j) {
    int p = j * 256 + t;
    int y = p >> 6, x = p & 63;
    const float* bp = &tl[y * 66 + x];
    float s;
    s = w00 * bp[0]        + w01 * bp[1]        + w02 * bp[2];
    s = fmaf(w10, bp[66],    fmaf(w11, bp[67],    fmaf(w12, bp[68],  s)));
    s = fmaf(w20, bp[132],   fmaf(w21, bp[133],   fmaf(w22, bp[134], s)));
    float v = (epi == 2) ? hswish(s * g + bb) : hswish(s + bb);
    op[p] = v;
  }
}

// Fused dw5x5(pad2) + grouped 1x1 (32->32 per group).
__global__ __launch_bounds__(256) void agg_fused(
    const float* __restrict__ in, const float* __restrict__ dw,
    const float* __restrict__ pw, float* __restrict__ out, int C)
{
  __shared__ float in_t[16 * 12 * 68];
  __shared__ float dww[32 * 25];
  __shared__ float pww[32 * 32];
  const int g = blockIdx.x, b = blockIdx.y, tile = blockIdx.z;
  const int t = threadIdx.x;
  const int y0 = tile * 8;
  const float* src = in + ((size_t)b * C + g * 32) * HW;

  for (int i = t; i < 800; i += 256)  dww[i] = dw[(size_t)g * 800 + i];
  for (int i = t; i < 1024; i += 256) pww[i] = pw[(size_t)g * 1024 + i];

  const int x = t & 63, yl = t >> 6;
  float acca[32] = {}, accb[32] = {};

  for (int ph = 0; ph < 2; ++ph) {
    __syncthreads();
    #pragma unroll
    for (int i = 0; i < 12; ++i) {
      int id = i * 256 + t;
      int q = id & 15;
      int rid = id >> 4;
      int ch = rid / 12, r = rid - ch * 12;
      int gy = y0 - 2 + r;
      float4 v = make_float4(0.f, 0.f, 0.f, 0.f);
      if (gy >= 0 && gy < 64)
        v = *(const float4*)(src + (size_t)(ph * 16 + ch) * HW + (gy << 6) + (q << 2));
      *(float4*)&in_t[(ch * 12 + r) * 68 + 2 + (q << 2)] = v;
    }
    #pragma unroll
    for (int i = 0; i < 3; ++i) {
      int id = i * 256 + t;
      int side = id & 3;
      int rid = id >> 2;
      int col = (side < 2) ? side : 64 + side;
      in_t[rid * 68 + col] = 0.0f;
    }
    __syncthreads();
    for (int cl = 0; cl < 16; ++cl) {
      int ci = ph * 16 + cl;
      const float* bp = &in_t[(cl * 12) * 68 + 2 + x];
      const float* wv = &dww[ci * 25];
      float da = 0.f, db = 0.f;
      #pragma unroll
      for (int k = 0; k < 25; ++k) {
        int dy = k / 5, dx = (k % 5) - 2;
        float w = wv[k];
        da = fmaf(w, bp[(yl + dy) * 68 + dx], da);
        db = fmaf(w, bp[(yl + 4 + dy) * 68 + dx], db);
      }
      #pragma unroll
      for (int m = 0; m < 32; ++m) {
        float w = pww[m * 32 + ci];
        acca[m] = fmaf(w, da, acca[m]);
        accb[m] = fmaf(w, db, accb[m]);
      }
    }
  }
  float* dst = out + ((size_t)b * C + g * 32) * HW + y0 * 64;
  #pragma unroll
  for (int m = 0; m < 32; ++m) {
    dst[(size_t)m * HW + (yl << 6) + x]        = acca[m];
    dst[(size_t)m * HW + ((yl + 4) << 6) + x]  = accb[m];
  }
}

// Attention phase A: partial ctx = K^T [V|1] over a 128-n slice, atomicAdd to ctxbuf.
__global__ __launch_bounds__(256) void att_ctx(
    const float* __restrict__ kv, const float* __restrict__ kvs,
    float* __restrict__ ctxbuf)
{
  __shared__ float kvt[64][129];
  const int head  = blockIdx.x;
  const int b     = blockIdx.y;
  const int slice = blockIdx.z & 31;
  const int z     = blockIdx.z >> 5;
  const int tid   = threadIdx.x;

  const float* kvsrc = (head < 8)
      ? kv  + ((size_t)b * 1024 + z * 512 + head * 64) * HW
      : kvs + ((size_t)b * 1024 + z * 512 + (head - 8) * 64) * HW;
  const int n0 = slice * 128;

  #pragma unroll
  for (int l = 0; l < 8; ++l) {
    int fid = tid + l * 256;
    int ch = fid >> 5;
    int nc = (fid & 31) << 2;
    float4 v = *(const float4*)(kvsrc + (size_t)ch * HW + n0 + nc);
    if (ch < 32) {
      v.x = fmaxf(v.x, 0.0f); v.y = fmaxf(v.y, 0.0f);
      v.z = fmaxf(v.z, 0.0f); v.w = fmaxf(v.w, 0.0f);
    }
    kvt[ch][nc] = v.x; kvt[ch][nc + 1] = v.y;
    kvt[ch][nc + 2] = v.z; kvt[ch][nc + 3] = v.w;
  }
  __syncthreads();

  const int td = tid & 15, te = tid >> 4;
  const int d0 = td * 2, e0 = te * 2;
  float a00 = 0, a01 = 0, a10 = 0, a11 = 0, c0 = 0, c1 = 0;
  #pragma unroll 8
  for (int nn = 0; nn < 128; ++nn) {
    float k0 = kvt[d0][nn], k1 = kvt[d0 + 1][nn];
    float v0 = kvt[32 + e0][nn], v1 = kvt[32 + e0 + 1][nn];
    a00 = fmaf(k0, v0, a00); a01 = fmaf(k0, v1, a01);
    a10 = fmaf(k1, v0, a10); a11 = fmaf(k1, v1, a11);
    c0 += k0; c1 += k1;
  }
  float* cp = ctxbuf + (size_t)(((z * 4 + b) * 16) + head) * 1056;
  atomic_add_f32(&cp[(d0 + 0) * 33 + e0 + 0], a00);
  atomic_add_f32(&cp[(d0 + 0) * 33 + e0 + 1], a01);
  atomic_add_f32(&cp[(d0 + 1) * 33 + e0 + 0], a10);
  atomic_add_f32(&cp[(d0 + 1) * 33 + e0 + 1], a11);
  if (te == 0) {
    atomic_add_f32(&cp[(d0 + 0) * 33 + 32], c0);
    atomic_add_f32(&cp[(d0 + 1) * 33 + 32], c1);
  }
}

// Attention phase B.
__global__ __launch_bounds__(256) void att_apply(
    const float* __restrict__ ctxbuf,
    const float* __restrict__ q0, const float* __restrict__ q0s,
    const float* __restrict__ q1, const float* __restrict__ q1s,
    float* __restrict__ outbase, size_t outstride)
{
  __shared__ float ctx[1056];
  const int head = blockIdx.x;
  const int b    = blockIdx.y;
  const int tile = blockIdx.z & 15;
  const int z    = blockIdx.z >> 4;
  const int tid  = threadIdx.x;

  const float* cp = ctxbuf + (size_t)(((z * 4 + b) * 16) + head) * 1056;
  for (int i = tid; i < 1056; i += 256) ctx[i] = cp[i];
  __syncthreads();

  const float* qb = (z == 0) ? (head < 8 ? q0 : q0s) : (head < 8 ? q1 : q1s);
  const float* qsrc = qb + ((size_t)b * 256 + (head & 7) * 32) * HW;
  float* outp = outbase + (size_t)z * outstride + ((size_t)b * 512 + head * 32) * HW;

  const int n = tile * 256 + tid;
  float qv[32];
  #pragma unroll
  for (int d = 0; d < 32; ++d)
    qv[d] = fmaxf(qsrc[(size_t)d * HW + n], 0.0f);
  float den = 1e-15f;
  #pragma unroll
  for (int d = 0; d < 32; ++d)
    den = fmaf(qv[d], ctx[d * 33 + 32], den);
  float rden = 1.0f / den;
  for (int e = 0; e < 32; ++e) {
    float s = 0.0f;
    #pragma unroll
    for (int d = 0; d < 32; ++d)
      s = fmaf(qv[d], ctx[d * 33 + e], s);
    outp[(size_t)e * HW + n] = s * rden;
  }
}

extern "C" void kernel_launch(void* const* d_in, const int* in_sizes, int n_in,
                              void* d_out, int out_size, void* d_ws, size_t ws_size,
                              hipStream_t stream) {
  (void)in_sizes; (void)n_in; (void)out_size; (void)ws_size;
  const float* rgb         = (const float*)d_in[0];
  const float* t           = (const float*)d_in[1];
  const float* m1_inv_w    = (const float*)d_in[2];
  const float* m1_inv_g    = (const float*)d_in[3];
  const float* m1_inv_b    = (const float*)d_in[4];
  const float* m1_dw_w     = (const float*)d_in[5];
  const float* m1_dw_g     = (const float*)d_in[6];
  const float* m1_dw_b     = (const float*)d_in[7];
  const float* m1_pw_w     = (const float*)d_in[8];
  const float* m1_pw_g     = (const float*)d_in[9];
  const float* m1_pw_b     = (const float*)d_in[10];
  const float* kv_w        = (const float*)d_in[11];
  const float* qrgb_w      = (const float*)d_in[12];
  const float* qt_w        = (const float*)d_in[13];
  const float* agg_kv_dw   = (const float*)d_in[14];
  const float* agg_kv_pw   = (const float*)d_in[15];
  const float* agg_t_dw    = (const float*)d_in[16];
  const float* agg_t_pw    = (const float*)d_in[17];
  const float* agg_rgb_dw  = (const float*)d_in[18];
  const float* agg_rgb_pw  = (const float*)d_in[19];
  const float* proj_w      = (const float*)d_in[20];
  const float* m2_inv_w    = (const float*)d_in[21];
  const float* m2_inv_bias = (const float*)d_in[22];
  const float* m2_dw_w     = (const float*)d_in[23];
  const float* m2_dw_bias  = (const float*)d_in[24];
  const float* m2_pw_w     = (const float*)d_in[25];
  const float* m2_pw_g     = (const float*)d_in[26];
  const float* m2_pw_b     = (const float*)d_in[27];
  float* outp = (float*)d_out;

  const size_t S = (size_t)4 * 256 * HW;   // one (B,256,64,64) fp32 tensor
  float* ws   = (float*)d_ws;
  float* bufA = ws;            // S
  float* bufB = ws + S;        // S
  float* bufE = ws + 2 * S;    // S (early: free; qt_s; late: WT for m2 phase)
  float* bufF = ws + 3 * S;    // S (early: WT for m1/proj phase; late: qrgb_s)
  float* KV   = ws + 4 * S;    // 4S (kv; later out1|out2)
  float* C4   = ws + 8 * S;    // 4S (ctxbuf; later m2_inv out)
  float* D4   = ws + 12 * S;   // 4S (kv_s; later m2_dw out)

  // transposed-weight slots (bufF early, bufE late)
  float* m1_invT = bufF;                 // 512*256  = 131072
  float* m1_pwT  = bufF + 131072;        // 256*256  =  65536
  float* kvT     = bufF + 196608;        // 256*1024 = 262144
  float* qtT     = bufF + 458752;        //           65536
  float* qrgbT   = bufF + 524288;        //           65536
  float* projT   = bufE;                 // 1024*256 = 262144
  float* m2_invT = bufE + 262144;        // 256*1024 = 262144
  float* m2_pwT  = bufE + 524288;        // 1024*256 = 262144

  dim3 blk(256);

  // early weight transposes (into bufF; consumed before agg_rgb overwrites)
  transpose_w<<<dim3(512),  blk, 0, stream>>>(m1_inv_w, m1_invT, 512, 255, 8);
  transpose_w<<<dim3(256),  blk, 0, stream>>>(m1_pw_w,  m1_pwT,  256, 255, 8);
  transpose_w<<<dim3(1024), blk, 0, stream>>>(kv_w,     kvT,     256, 1023, 10);
  transpose_w<<<dim3(256),  blk, 0, stream>>>(qt_w,     qtT,     256, 255, 8);
  transpose_w<<<dim3(256),  blk, 0, stream>>>(qrgb_w,   qrgbT,   256, 255, 8);

  // m1 stem
  gemm1x1_sw<<<dim3(16, 8, 4), blk, 0, stream>>>(rgb, t, m1_invT, bufA, m1_inv_g, m1_inv_b, 512, 256, 256, 2);
  dwconv3<<<dim3(1024), blk, 0, stream>>>(bufA, m1_dw_w, bufB, m1_dw_g, m1_dw_b, 255, 2);
  gemm1x1_sw<<<dim3(16, 8, 4), blk, 0, stream>>>(bufB, bufB, m1_pwT, bufA, m1_pw_g, m1_pw_b, 256, 256, 256, 1); // rgbt -> A

  // projections
  gemm1x1_sw<<<dim3(16, 32, 4), blk, 0, stream>>>(bufA, bufA, kvT, KV, nullptr, nullptr, 256, 256, 1024, 0);    // kv
  gemm1x1_sw<<<dim3(16, 8, 4), blk, 0, stream>>>(t, t, qtT, bufB, nullptr, nullptr, 256, 256, 256, 0);          // q_t -> B
  gemm1x1_sw<<<dim3(16, 8, 4), blk, 0, stream>>>(rgb, rgb, qrgbT, bufA, nullptr, nullptr, 256, 256, 256, 0);    // q_rgb -> A

  // fused multi-scale aggregation (dw5x5 + grouped 1x1)
  agg_fused<<<dim3(32, 4, 8), blk, 0, stream>>>(KV,  agg_kv_dw,  agg_kv_pw,  D4,  1024);  // kv_s -> D4
  agg_fused<<<dim3(8, 4, 8),  blk, 0, stream>>>(bufB, agg_t_dw,  agg_t_pw,  bufE, 256);   // qt_s -> E
  agg_fused<<<dim3(8, 4, 8),  blk, 0, stream>>>(bufA, agg_rgb_dw, agg_rgb_pw, bufF, 256); // qrgb_s -> F

  // attention
  zero_buf4<<<dim3(132), blk, 0, stream>>>((float4*)C4, 128 * 264);
  att_ctx<<<dim3(16, 4, 64), blk, 0, stream>>>(KV, D4, C4);
  att_apply<<<dim3(16, 4, 32), blk, 0, stream>>>(C4, bufB, bufE, bufA, bufF, KV, 2 * S);

  // late weight transposes (into bufE; qt_s already consumed)
  transpose_w<<<dim3(1024), blk, 0, stream>>>(proj_w,   projT,   1024, 255, 8);
  transpose_w<<<dim3(1024), blk, 0, stream>>>(m2_inv_w, m2_invT, 256, 1023, 10);
  transpose_w<<<dim3(1024), blk, 0, stream>>>(m2_pw_w,  m2_pwT,  1024, 255, 8);

  // projection + m2 tail
  gemm1x1_sw<<<dim3(16, 8, 4), blk, 0, stream>>>(KV, KV + 2 * S, projT, bufB, nullptr, nullptr, 1024, 512, 256, 0);
  gemm1x1_sw<<<dim3(16, 32, 4), blk, 0, stream>>>(bufB, bufB, m2_invT, C4, nullptr, m2_inv_bias, 256, 256, 1024, 3);
  dwconv3<<<dim3(4096), blk, 0, stream>>>(C4, m2_dw_w, D4, nullptr, m2_dw_bias, 1023, 3);
  gemm1x1_sw<<<dim3(16, 8, 4), blk, 0, stream>>>(D4, D4, m2_pwT, outp, m2_pw_g, m2_pw_b, 1024, 1024, 256, 1);
}

// Round 8
// 1669.390 us; speedup vs baseline: 1.0064x; 1.0064x over previous
//
#include <hip/hip_runtime.h>

#define HW 4096

__device__ __forceinline__ float hswish(float x) {
  float r = fminf(fmaxf(x + 3.0f, 0.0f), 6.0f);
  return x * r * (1.0f / 6.0f);
}

__device__ __forceinline__ void atomic_add_f32(float* p, float v) {
  __hip_atomic_fetch_add(p, v, __ATOMIC_RELAXED, __HIP_MEMORY_SCOPE_AGENT);
}

__global__ __launch_bounds__(256) void zero_buf4(float4* __restrict__ p, int n4) {
  int i = blockIdx.x * 256 + threadIdx.x;
  if (i < n4) p[i] = make_float4(0.f, 0.f, 0.f, 0.f);
}

// Transpose W[CO][K] -> WT[K][CO]. CO, K powers of two. Coalesced writes.
__global__ __launch_bounds__(256) void transpose_w(
    const float* __restrict__ in, float* __restrict__ out,
    int K, int comask, int coshift)
{
  int i = blockIdx.x * 256 + threadIdx.x;   // i = k*CO + co
  int co = i & comask;
  int k  = i >> coshift;
  out[i] = in[(size_t)co * K + k];
}

// Scalar-broadcast 1x1-conv GEMM. 256 threads = 256 spatial positions (one per
// lane); each thread accumulates 32 consecutive co. W operand comes from WT[K][CO]
// via block-uniform indices -> SGPR s_load broadcast (zero LDS traffic for W).
// A staged in LDS [32][256], one conflict-free ds_read_b32 per 32 FMAs.
// NOTE: every loop touching acc[] MUST be fully unrolled; a partial unroll
// leaves a runtime index -> acc demoted to scratch -> 20x write traffic (R7 bug).
// Grid dim3(16, CO/32, 4). epi: 0 none, 1 g*x+b, 2 hswish(g*x+b), 3 hswish(x+b)
__global__ __launch_bounds__(256) void gemm1x1_sw(
    const float* __restrict__ in0, const float* __restrict__ in1,
    const float* __restrict__ WT, float* __restrict__ out,
    const float* __restrict__ scale, const float* __restrict__ bias,
    int K, int k0, int CO, int epi)
{
  __shared__ float At[32][256];   // 32 KB
  const int p0  = blockIdx.x * 256;
  const int co0 = blockIdx.y * 32;
  const int b   = blockIdx.z;
  const int t   = threadIdx.x;
  const int k1  = K - k0;

  float acc[32] = {};
  float4 st[8];

  // prologue: stage K-tile 0 into regs
  #pragma unroll
  for (int j = 0; j < 8; ++j) {
    int id = j * 256 + t;
    int r = id >> 6, c = (id & 63) << 2;
    const float* src = (r < k0)
        ? in0 + ((size_t)b * k0 + r) * HW
        : in1 + ((size_t)b * k1 + (r - k0)) * HW;
    st[j] = *(const float4*)(src + p0 + c);
  }

  for (int kt = 0; kt < K; kt += 32) {
    #pragma unroll
    for (int j = 0; j < 8; ++j) {
      int id = j * 256 + t;
      int r = id >> 6, c = (id & 63) << 2;
      *(float4*)&At[r][c] = st[j];
    }
    __syncthreads();
    if (kt + 32 < K) {
      #pragma unroll
      for (int j = 0; j < 8; ++j) {
        int id = j * 256 + t;
        int r = kt + 32 + (id >> 6), c = (id & 63) << 2;
        const float* src = (r < k0)
            ? in0 + ((size_t)b * k0 + r) * HW
            : in1 + ((size_t)b * k1 + (r - k0)) * HW;
        st[j] = *(const float4*)(src + p0 + c);
      }
    }
    const float* wp = WT + (size_t)kt * CO + co0;   // block-uniform
    #pragma unroll 4
    for (int k = 0; k < 32; ++k) {
      float a = At[k][t];
      const float* wr = wp + (size_t)k * CO;        // block-uniform row
      #pragma unroll
      for (int i = 0; i < 32; ++i)
        acc[i] = fmaf(wr[i], a, acc[i]);            // SGPR * VGPR fma
    }
    __syncthreads();
  }

  float* op = out + ((size_t)b * CO + co0) * HW + p0 + t;
  #pragma unroll
  for (int i = 0; i < 32; ++i) {
    int co = co0 + i;
    float v = acc[i];
    if (epi == 1)      v = v * scale[co] + bias[co];
    else if (epi == 2) v = hswish(v * scale[co] + bias[co]);
    else if (epi == 3) v = hswish(v + bias[co]);
    op[(size_t)i * HW] = v;
  }
}

// LDS-tiled depthwise 3x3, pad 1, branch-free inner loop. One block per (b,c).
// epi: 2 hswish(scale*x+bias), 3 hswish(x+bias)
__global__ __launch_bounds__(256) void dwconv3(
    const float* __restrict__ in, const float* __restrict__ w,
    float* __restrict__ out, const float* __restrict__ scale,
    const float* __restrict__ bias, int Cmask, int epi)
{
  __shared__ float tl[66 * 66];
  const int bc = blockIdx.x;
  const int c  = bc & Cmask;
  const float* src = in + (size_t)bc * HW;
  const int t = threadIdx.x;
  for (int i = t; i < 66 * 66; i += 256) {
    int r = i / 66, cc = i - r * 66;
    int gy = r - 1, gx = cc - 1;
    float v = 0.0f;
    if (gy >= 0 && gy < 64 && gx >= 0 && gx < 64) v = src[(gy << 6) + gx];
    tl[i] = v;
  }
  const float* wp = w + c * 9;
  float w00 = wp[0], w01 = wp[1], w02 = wp[2];
  float w10 = wp[3], w11 = wp[4], w12 = wp[5];
  float w20 = wp[6], w21 = wp[7], w22 = wp[8];
  float g = (epi == 2) ? scale[c] : 1.0f;
  float bb = bias[c];
  __syncthreads();
  float* op = out + (size_t)bc * HW;
  #pragma unroll 4
  for (int j = 0; j < 16; ++j) {
    int p = j * 256 + t;
    int y = p >> 6, x = p & 63;
    const float* bp = &tl[y * 66 + x];
    float s;
    s = w00 * bp[0]        + w01 * bp[1]        + w02 * bp[2];
    s = fmaf(w10, bp[66],    fmaf(w11, bp[67],    fmaf(w12, bp[68],  s)));
    s = fmaf(w20, bp[132],   fmaf(w21, bp[133],   fmaf(w22, bp[134], s)));
    float v = (epi == 2) ? hswish(s * g + bb) : hswish(s + bb);
    op[p] = v;
  }
}

// Fused dw5x5(pad2) + grouped 1x1 (32->32 per group).
__global__ __launch_bounds__(256) void agg_fused(
    const float* __restrict__ in, const float* __restrict__ dw,
    const float* __restrict__ pw, float* __restrict__ out, int C)
{
  __shared__ float in_t[16 * 12 * 68];
  __shared__ float dww[32 * 25];
  __shared__ float pww[32 * 32];
  const int g = blockIdx.x, b = blockIdx.y, tile = blockIdx.z;
  const int t = threadIdx.x;
  const int y0 = tile * 8;
  const float* src = in + ((size_t)b * C + g * 32) * HW;

  for (int i = t; i < 800; i += 256)  dww[i] = dw[(size_t)g * 800 + i];
  for (int i = t; i < 1024; i += 256) pww[i] = pw[(size_t)g * 1024 + i];

  const int x = t & 63, yl = t >> 6;
  float acca[32] = {}, accb[32] = {};

  for (int ph = 0; ph < 2; ++ph) {
    __syncthreads();
    #pragma unroll
    for (int i = 0; i < 12; ++i) {
      int id = i * 256 + t;
      int q = id & 15;
      int rid = id >> 4;
      int ch = rid / 12, r = rid - ch * 12;
      int gy = y0 - 2 + r;
      float4 v = make_float4(0.f, 0.f, 0.f, 0.f);
      if (gy >= 0 && gy < 64)
        v = *(const float4*)(src + (size_t)(ph * 16 + ch) * HW + (gy << 6) + (q << 2));
      *(float4*)&in_t[(ch * 12 + r) * 68 + 2 + (q << 2)] = v;
    }
    #pragma unroll
    for (int i = 0; i < 3; ++i) {
      int id = i * 256 + t;
      int side = id & 3;
      int rid = id >> 2;
      int col = (side < 2) ? side : 64 + side;
      in_t[rid * 68 + col] = 0.0f;
    }
    __syncthreads();
    for (int cl = 0; cl < 16; ++cl) {
      int ci = ph * 16 + cl;
      const float* bp = &in_t[(cl * 12) * 68 + 2 + x];
      const float* wv = &dww[ci * 25];
      float da = 0.f, db = 0.f;
      #pragma unroll
      for (int k = 0; k < 25; ++k) {
        int dy = k / 5, dx = (k % 5) - 2;
        float w = wv[k];
        da = fmaf(w, bp[(yl + dy) * 68 + dx], da);
        db = fmaf(w, bp[(yl + 4 + dy) * 68 + dx], db);
      }
      #pragma unroll
      for (int m = 0; m < 32; ++m) {
        float w = pww[m * 32 + ci];
        acca[m] = fmaf(w, da, acca[m]);
        accb[m] = fmaf(w, db, accb[m]);
      }
    }
  }
  float* dst = out + ((size_t)b * C + g * 32) * HW + y0 * 64;
  #pragma unroll
  for (int m = 0; m < 32; ++m) {
    dst[(size_t)m * HW + (yl << 6) + x]        = acca[m];
    dst[(size_t)m * HW + ((yl + 4) << 6) + x]  = accb[m];
  }
}

// Attention phase A: partial ctx = K^T [V|1] over a 128-n slice, atomicAdd to ctxbuf.
__global__ __launch_bounds__(256) void att_ctx(
    const float* __restrict__ kv, const float* __restrict__ kvs,
    float* __restrict__ ctxbuf)
{
  __shared__ float kvt[64][129];
  const int head  = blockIdx.x;
  const int b     = blockIdx.y;
  const int slice = blockIdx.z & 31;
  const int z     = blockIdx.z >> 5;
  const int tid   = threadIdx.x;

  const float* kvsrc = (head < 8)
      ? kv  + ((size_t)b * 1024 + z * 512 + head * 64) * HW
      : kvs + ((size_t)b * 1024 + z * 512 + (head - 8) * 64) * HW;
  const int n0 = slice * 128;

  #pragma unroll
  for (int l = 0; l < 8; ++l) {
    int fid = tid + l * 256;
    int ch = fid >> 5;
    int nc = (fid & 31) << 2;
    float4 v = *(const float4*)(kvsrc + (size_t)ch * HW + n0 + nc);
    if (ch < 32) {
      v.x = fmaxf(v.x, 0.0f); v.y = fmaxf(v.y, 0.0f);
      v.z = fmaxf(v.z, 0.0f); v.w = fmaxf(v.w, 0.0f);
    }
    kvt[ch][nc] = v.x; kvt[ch][nc + 1] = v.y;
    kvt[ch][nc + 2] = v.z; kvt[ch][nc + 3] = v.w;
  }
  __syncthreads();

  const int td = tid & 15, te = tid >> 4;
  const int d0 = td * 2, e0 = te * 2;
  float a00 = 0, a01 = 0, a10 = 0, a11 = 0, c0 = 0, c1 = 0;
  #pragma unroll 8
  for (int nn = 0; nn < 128; ++nn) {
    float k0 = kvt[d0][nn], k1 = kvt[d0 + 1][nn];
    float v0 = kvt[32 + e0][nn], v1 = kvt[32 + e0 + 1][nn];
    a00 = fmaf(k0, v0, a00); a01 = fmaf(k0, v1, a01);
    a10 = fmaf(k1, v0, a10); a11 = fmaf(k1, v1, a11);
    c0 += k0; c1 += k1;
  }
  float* cp = ctxbuf + (size_t)(((z * 4 + b) * 16) + head) * 1056;
  atomic_add_f32(&cp[(d0 + 0) * 33 + e0 + 0], a00);
  atomic_add_f32(&cp[(d0 + 0) * 33 + e0 + 1], a01);
  atomic_add_f32(&cp[(d0 + 1) * 33 + e0 + 0], a10);
  atomic_add_f32(&cp[(d0 + 1) * 33 + e0 + 1], a11);
  if (te == 0) {
    atomic_add_f32(&cp[(d0 + 0) * 33 + 32], c0);
    atomic_add_f32(&cp[(d0 + 1) * 33 + 32], c1);
  }
}

// Attention phase B.
__global__ __launch_bounds__(256) void att_apply(
    const float* __restrict__ ctxbuf,
    const float* __restrict__ q0, const float* __restrict__ q0s,
    const float* __restrict__ q1, const float* __restrict__ q1s,
    float* __restrict__ outbase, size_t outstride)
{
  __shared__ float ctx[1056];
  const int head = blockIdx.x;
  const int b    = blockIdx.y;
  const int tile = blockIdx.z & 15;
  const int z    = blockIdx.z >> 4;
  const int tid  = threadIdx.x;

  const float* cp = ctxbuf + (size_t)(((z * 4 + b) * 16) + head) * 1056;
  for (int i = tid; i < 1056; i += 256) ctx[i] = cp[i];
  __syncthreads();

  const float* qb = (z == 0) ? (head < 8 ? q0 : q0s) : (head < 8 ? q1 : q1s);
  const float* qsrc = qb + ((size_t)b * 256 + (head & 7) * 32) * HW;
  float* outp = outbase + (size_t)z * outstride + ((size_t)b * 512 + head * 32) * HW;

  const int n = tile * 256 + tid;
  float qv[32];
  #pragma unroll
  for (int d = 0; d < 32; ++d)
    qv[d] = fmaxf(qsrc[(size_t)d * HW + n], 0.0f);
  float den = 1e-15f;
  #pragma unroll
  for (int d = 0; d < 32; ++d)
    den = fmaf(qv[d], ctx[d * 33 + 32], den);
  float rden = 1.0f / den;
  for (int e = 0; e < 32; ++e) {
    float s = 0.0f;
    #pragma unroll
    for (int d = 0; d < 32; ++d)
      s = fmaf(qv[d], ctx[d * 33 + e], s);
    outp[(size_t)e * HW + n] = s * rden;
  }
}

extern "C" void kernel_launch(void* const* d_in, const int* in_sizes, int n_in,
                              void* d_out, int out_size, void* d_ws, size_t ws_size,
                              hipStream_t stream) {
  (void)in_sizes; (void)n_in; (void)out_size; (void)ws_size;
  const float* rgb         = (const float*)d_in[0];
  const float* t           = (const float*)d_in[1];
  const float* m1_inv_w    = (const float*)d_in[2];
  const float* m1_inv_g    = (const float*)d_in[3];
  const float* m1_inv_b    = (const float*)d_in[4];
  const float* m1_dw_w     = (const float*)d_in[5];
  const float* m1_dw_g     = (const float*)d_in[6];
  const float* m1_dw_b     = (const float*)d_in[7];
  const float* m1_pw_w     = (const float*)d_in[8];
  const float* m1_pw_g     = (const float*)d_in[9];
  const float* m1_pw_b     = (const float*)d_in[10];
  const float* kv_w        = (const float*)d_in[11];
  const float* qrgb_w      = (const float*)d_in[12];
  const float* qt_w        = (const float*)d_in[13];
  const float* agg_kv_dw   = (const float*)d_in[14];
  const float* agg_kv_pw   = (const float*)d_in[15];
  const float* agg_t_dw    = (const float*)d_in[16];
  const float* agg_t_pw    = (const float*)d_in[17];
  const float* agg_rgb_dw  = (const float*)d_in[18];
  const float* agg_rgb_pw  = (const float*)d_in[19];
  const float* proj_w      = (const float*)d_in[20];
  const float* m2_inv_w    = (const float*)d_in[21];
  const float* m2_inv_bias = (const float*)d_in[22];
  const float* m2_dw_w     = (const float*)d_in[23];
  const float* m2_dw_bias  = (const float*)d_in[24];
  const float* m2_pw_w     = (const float*)d_in[25];
  const float* m2_pw_g     = (const float*)d_in[26];
  const float* m2_pw_b     = (const float*)d_in[27];
  float* outp = (float*)d_out;

  const size_t S = (size_t)4 * 256 * HW;   // one (B,256,64,64) fp32 tensor
  float* ws   = (float*)d_ws;
  float* bufA = ws;            // S
  float* bufB = ws + S;        // S
  float* bufE = ws + 2 * S;    // S (early: free; qt_s; late: WT for m2 phase)
  float* bufF = ws + 3 * S;    // S (early: WT for m1/proj phase; late: qrgb_s)
  float* KV   = ws + 4 * S;    // 4S (kv; later out1|out2)
  float* C4   = ws + 8 * S;    // 4S (ctxbuf; later m2_inv out)
  float* D4   = ws + 12 * S;   // 4S (kv_s; later m2_dw out)

  // transposed-weight slots (bufF early, bufE late)
  float* m1_invT = bufF;                 // 512*256  = 131072
  float* m1_pwT  = bufF + 131072;        // 256*256  =  65536
  float* kvT     = bufF + 196608;        // 256*1024 = 262144
  float* qtT     = bufF + 458752;        //           65536
  float* qrgbT   = bufF + 524288;        //           65536
  float* projT   = bufE;                 // 1024*256 = 262144
  float* m2_invT = bufE + 262144;        // 256*1024 = 262144
  float* m2_pwT  = bufE + 524288;        // 1024*256 = 262144

  dim3 blk(256);

  // early weight transposes (into bufF; consumed before agg_rgb overwrites)
  transpose_w<<<dim3(512),  blk, 0, stream>>>(m1_inv_w, m1_invT, 512, 255, 8);
  transpose_w<<<dim3(256),  blk, 0, stream>>>(m1_pw_w,  m1_pwT,  256, 255, 8);
  transpose_w<<<dim3(1024), blk, 0, stream>>>(kv_w,     kvT,     256, 1023, 10);
  transpose_w<<<dim3(256),  blk, 0, stream>>>(qt_w,     qtT,     256, 255, 8);
  transpose_w<<<dim3(256),  blk, 0, stream>>>(qrgb_w,   qrgbT,   256, 255, 8);

  // m1 stem
  gemm1x1_sw<<<dim3(16, 8, 4), blk, 0, stream>>>(rgb, t, m1_invT, bufA, m1_inv_g, m1_inv_b, 512, 256, 256, 2);
  dwconv3<<<dim3(1024), blk, 0, stream>>>(bufA, m1_dw_w, bufB, m1_dw_g, m1_dw_b, 255, 2);
  gemm1x1_sw<<<dim3(16, 8, 4), blk, 0, stream>>>(bufB, bufB, m1_pwT, bufA, m1_pw_g, m1_pw_b, 256, 256, 256, 1); // rgbt -> A

  // projections
  gemm1x1_sw<<<dim3(16, 32, 4), blk, 0, stream>>>(bufA, bufA, kvT, KV, nullptr, nullptr, 256, 256, 1024, 0);    // kv
  gemm1x1_sw<<<dim3(16, 8, 4), blk, 0, stream>>>(t, t, qtT, bufB, nullptr, nullptr, 256, 256, 256, 0);          // q_t -> B
  gemm1x1_sw<<<dim3(16, 8, 4), blk, 0, stream>>>(rgb, rgb, qrgbT, bufA, nullptr, nullptr, 256, 256, 256, 0);    // q_rgb -> A

  // fused multi-scale aggregation (dw5x5 + grouped 1x1)
  agg_fused<<<dim3(32, 4, 8), blk, 0, stream>>>(KV,  agg_kv_dw,  agg_kv_pw,  D4,  1024);  // kv_s -> D4
  agg_fused<<<dim3(8, 4, 8),  blk, 0, stream>>>(bufB, agg_t_dw,  agg_t_pw,  bufE, 256);   // qt_s -> E
  agg_fused<<<dim3(8, 4, 8),  blk, 0, stream>>>(bufA, agg_rgb_dw, agg_rgb_pw, bufF, 256); // qrgb_s -> F

  // attention
  zero_buf4<<<dim3(132), blk, 0, stream>>>((float4*)C4, 128 * 264);
  att_ctx<<<dim3(16, 4, 64), blk, 0, stream>>>(KV, D4, C4);
  att_apply<<<dim3(16, 4, 32), blk, 0, stream>>>(C4, bufB, bufE, bufA, bufF, KV, 2 * S);

  // late weight transposes (into bufE; qt_s already consumed)
  transpose_w<<<dim3(1024), blk, 0, stream>>>(proj_w,   projT,   1024, 255, 8);
  transpose_w<<<dim3(1024), blk, 0, stream>>>(m2_inv_w, m2_invT, 256, 1023, 10);
  transpose_w<<<dim3(1024), blk, 0, stream>>>(m2_pw_w,  m2_pwT,  1024, 255, 8);

  // projection + m2 tail
  gemm1x1_sw<<<dim3(16, 8, 4), blk, 0, stream>>>(KV, KV + 2 * S, projT, bufB, nullptr, nullptr, 1024, 512, 256, 0);
  gemm1x1_sw<<<dim3(16, 32, 4), blk, 0, stream>>>(bufB, bufB, m2_invT, C4, nullptr, m2_inv_bias, 256, 256, 1024, 3);
  dwconv3<<<dim3(4096), blk, 0, stream>>>(C4, m2_dw_w, D4, nullptr, m2_dw_bias, 1023, 3);
  gemm1x1_sw<<<dim3(16, 8, 4), blk, 0, stream>>>(D4, D4, m2_pwT, outp, m2_pw_g, m2_pw_b, 1024, 1024, 256, 1);
}

// Round 9
// 1117.736 us; speedup vs baseline: 1.5030x; 1.4935x over previous
//
#include <hip/hip_runtime.h>

#define HW 4096

__device__ __forceinline__ float hswish(float x) {
  float r = fminf(fmaxf(x + 3.0f, 0.0f), 6.0f);
  return x * r * (1.0f / 6.0f);
}

__device__ __forceinline__ void atomic_add_f32(float* p, float v) {
  __hip_atomic_fetch_add(p, v, __ATOMIC_RELAXED, __HIP_MEMORY_SCOPE_AGENT);
}

__global__ __launch_bounds__(256) void zero_buf4(float4* __restrict__ p, int n4) {
  int i = blockIdx.x * 256 + threadIdx.x;
  if (i < n4) p[i] = make_float4(0.f, 0.f, 0.f, 0.f);
}

// 1x1 conv GEMM, 128x128 tile, 8x8/thread. Grid dim3(32, CO/128, B).
// epi: 0 none, 3 hswish(x+bias). (Used for CO=1024: kv, m2_inv.)
__global__ __launch_bounds__(256) void gemm1x1_big(
    const float* __restrict__ in0, const float* __restrict__ in1,
    const float* __restrict__ W, float* __restrict__ out,
    const float* __restrict__ scale, const float* __restrict__ bias,
    int K, int k0, int CO, int epi)
{
  __shared__ float At[8][128];
  __shared__ float Wt[8][128];
  const int p0  = blockIdx.x * 128;
  const int co0 = blockIdx.y * 128;
  const int b   = blockIdx.z;
  const int tid = threadIdx.x;
  const int tx = tid & 15, ty = tid >> 4;
  const int k1 = K - k0;
  const int ar = tid >> 5, ac = (tid & 31) << 2;
  const int wco = tid >> 1, wk = (tid & 1) << 2;
  float acc[8][8] = {};
  for (int kt = 0; kt < K; kt += 8) {
    {
      int kg = kt + ar;
      const float* src = (kg < k0)
          ? in0 + ((size_t)b * k0 + kg) * HW
          : in1 + ((size_t)b * k1 + (kg - k0)) * HW;
      *(float4*)&At[ar][ac] = *(const float4*)(src + p0 + ac);
    }
    {
      float4 wv = *(const float4*)(W + (size_t)(co0 + wco) * K + kt + wk);
      Wt[wk + 0][wco] = wv.x; Wt[wk + 1][wco] = wv.y;
      Wt[wk + 2][wco] = wv.z; Wt[wk + 3][wco] = wv.w;
    }
    __syncthreads();
    #pragma unroll
    for (int k = 0; k < 8; ++k) {
      float4 a0 = *(const float4*)&At[k][tx << 2];
      float4 a1 = *(const float4*)&At[k][(tx << 2) + 64];
      float4 w0 = *(const float4*)&Wt[k][ty << 2];
      float4 w1 = *(const float4*)&Wt[k][(ty << 2) + 64];
      float av[8] = {a0.x, a0.y, a0.z, a0.w, a1.x, a1.y, a1.z, a1.w};
      float wv[8] = {w0.x, w0.y, w0.z, w0.w, w1.x, w1.y, w1.z, w1.w};
      #pragma unroll
      for (int i = 0; i < 8; ++i)
        #pragma unroll
        for (int j = 0; j < 8; ++j)
          acc[i][j] = fmaf(wv[i], av[j], acc[i][j]);
    }
    __syncthreads();
  }
  #pragma unroll
  for (int i = 0; i < 8; ++i) {
    int co = co0 + (ty << 2) + (i & 3) + (i >> 2) * 64;
    float bb = (epi == 3) ? bias[co] : 0.0f;
    float vv[8];
    #pragma unroll
    for (int j = 0; j < 8; ++j) {
      float v = acc[i][j];
      if (epi == 3) v = hswish(v + bb);
      vv[j] = v;
    }
    float* op = out + ((size_t)b * CO + co) * HW + p0;
    *(float4*)(op + (tx << 2))      = make_float4(vv[0], vv[1], vv[2], vv[3]);
    *(float4*)(op + (tx << 2) + 64) = make_float4(vv[4], vv[5], vv[6], vv[7]);
  }
}

// Split-K=4 variant: block s handles K range [s*kc, (s+1)*kc), stores its partial
// to pbuf + s*(B*CO*HW) with plain coalesced float4 stores (NO atomics - R5 lesson).
// Grid dim3(32, CO/128, B*4): s = z&3, b = z>>2.
__global__ __launch_bounds__(256) void gemm1x1_bigsplit(
    const float* __restrict__ in0, const float* __restrict__ in1,
    const float* __restrict__ W, float* __restrict__ pbuf,
    int K, int k0, int CO, int kc)
{
  __shared__ float At[8][128];
  __shared__ float Wt[8][128];
  const int p0  = blockIdx.x * 128;
  const int co0 = blockIdx.y * 128;
  const int s   = blockIdx.z & 3;
  const int b   = blockIdx.z >> 2;
  const int tid = threadIdx.x;
  const int tx = tid & 15, ty = tid >> 4;
  const int k1 = K - k0;
  const int ar = tid >> 5, ac = (tid & 31) << 2;
  const int wco = tid >> 1, wk = (tid & 1) << 2;
  const int kbeg = s * kc, kend = kbeg + kc;
  float acc[8][8] = {};
  for (int kt = kbeg; kt < kend; kt += 8) {
    {
      int kg = kt + ar;
      const float* src = (kg < k0)
          ? in0 + ((size_t)b * k0 + kg) * HW
          : in1 + ((size_t)b * k1 + (kg - k0)) * HW;
      *(float4*)&At[ar][ac] = *(const float4*)(src + p0 + ac);
    }
    {
      float4 wv = *(const float4*)(W + (size_t)(co0 + wco) * K + kt + wk);
      Wt[wk + 0][wco] = wv.x; Wt[wk + 1][wco] = wv.y;
      Wt[wk + 2][wco] = wv.z; Wt[wk + 3][wco] = wv.w;
    }
    __syncthreads();
    #pragma unroll
    for (int k = 0; k < 8; ++k) {
      float4 a0 = *(const float4*)&At[k][tx << 2];
      float4 a1 = *(const float4*)&At[k][(tx << 2) + 64];
      float4 w0 = *(const float4*)&Wt[k][ty << 2];
      float4 w1 = *(const float4*)&Wt[k][(ty << 2) + 64];
      float av[8] = {a0.x, a0.y, a0.z, a0.w, a1.x, a1.y, a1.z, a1.w};
      float wv[8] = {w0.x, w0.y, w0.z, w0.w, w1.x, w1.y, w1.z, w1.w};
      #pragma unroll
      for (int i = 0; i < 8; ++i)
        #pragma unroll
        for (int j = 0; j < 8; ++j)
          acc[i][j] = fmaf(wv[i], av[j], acc[i][j]);
    }
    __syncthreads();
  }
  float* pb = pbuf + (size_t)s * ((size_t)4 * CO * HW);
  #pragma unroll
  for (int i = 0; i < 8; ++i) {
    int co = co0 + (ty << 2) + (i & 3) + (i >> 2) * 64;
    float* op = pb + ((size_t)b * CO + co) * HW + p0;
    *(float4*)(op + (tx << 2))      = make_float4(acc[i][0], acc[i][1], acc[i][2], acc[i][3]);
    *(float4*)(op + (tx << 2) + 64) = make_float4(acc[i][4], acc[i][5], acc[i][6], acc[i][7]);
  }
}

// Reduce 4 partials + epilogue. CO=256 only (Cmask=255).
// mode: 0 none, 1 g*x+b, 2 hswish(g*x+b). Grid 4096 blocks.
__global__ __launch_bounds__(256) void reduce4_epi(
    const float4* __restrict__ p, float4* __restrict__ out,
    const float* __restrict__ scale, const float* __restrict__ bias, int mode)
{
  const size_t st4 = (size_t)4 * 256 * HW / 4;   // one partial, in float4s
  int i = blockIdx.x * 256 + threadIdx.x;
  float4 a = p[i], b1 = p[i + st4], c2 = p[i + 2 * st4], d = p[i + 3 * st4];
  float4 v = make_float4(a.x + b1.x + c2.x + d.x, a.y + b1.y + c2.y + d.y,
                         a.z + b1.z + c2.z + d.z, a.w + b1.w + c2.w + d.w);
  if (mode != 0) {
    int c = (i >> 10) & 255;
    float g = scale[c], bb = bias[c];
    float* f = &v.x;
    #pragma unroll
    for (int j = 0; j < 4; ++j) {
      float x = f[j] * g + bb;
      f[j] = (mode == 2) ? hswish(x) : x;
    }
  }
  out[i] = v;
}

// LDS-tiled depthwise 3x3, pad 1, branch-free inner loop. One block per (b,c).
// epi: 2 hswish(scale*x+bias), 3 hswish(x+bias)
__global__ __launch_bounds__(256) void dwconv3(
    const float* __restrict__ in, const float* __restrict__ w,
    float* __restrict__ out, const float* __restrict__ scale,
    const float* __restrict__ bias, int Cmask, int epi)
{
  __shared__ float tl[66 * 66];
  const int bc = blockIdx.x;
  const int c  = bc & Cmask;
  const float* src = in + (size_t)bc * HW;
  const int t = threadIdx.x;
  for (int i = t; i < 66 * 66; i += 256) {
    int r = i / 66, cc = i - r * 66;
    int gy = r - 1, gx = cc - 1;
    float v = 0.0f;
    if (gy >= 0 && gy < 64 && gx >= 0 && gx < 64) v = src[(gy << 6) + gx];
    tl[i] = v;
  }
  const float* wp = w + c * 9;
  float w00 = wp[0], w01 = wp[1], w02 = wp[2];
  float w10 = wp[3], w11 = wp[4], w12 = wp[5];
  float w20 = wp[6], w21 = wp[7], w22 = wp[8];
  float g = (epi == 2) ? scale[c] : 1.0f;
  float bb = bias[c];
  __syncthreads();
  float* op = out + (size_t)bc * HW;
  #pragma unroll 4
  for (int j = 0; j < 16; ++j) {
    int p = j * 256 + t;
    int y = p >> 6, x = p & 63;
    const float* bp = &tl[y * 66 + x];
    float s;
    s = w00 * bp[0]        + w01 * bp[1]        + w02 * bp[2];
    s = fmaf(w10, bp[66],    fmaf(w11, bp[67],    fmaf(w12, bp[68],  s)));
    s = fmaf(w20, bp[132],   fmaf(w21, bp[133],   fmaf(w22, bp[134], s)));
    float v = (epi == 2) ? hswish(s * g + bb) : hswish(s + bb);
    op[p] = v;
  }
}

// Fused dw5x5(pad2) + grouped 1x1 (32->32 per group).
__global__ __launch_bounds__(256) void agg_fused(
    const float* __restrict__ in, const float* __restrict__ dw,
    const float* __restrict__ pw, float* __restrict__ out, int C)
{
  __shared__ float in_t[16 * 12 * 68];
  __shared__ float dww[32 * 25];
  __shared__ float pww[32 * 32];
  const int g = blockIdx.x, b = blockIdx.y, tile = blockIdx.z;
  const int t = threadIdx.x;
  const int y0 = tile * 8;
  const float* src = in + ((size_t)b * C + g * 32) * HW;

  for (int i = t; i < 800; i += 256)  dww[i] = dw[(size_t)g * 800 + i];
  for (int i = t; i < 1024; i += 256) pww[i] = pw[(size_t)g * 1024 + i];

  const int x = t & 63, yl = t >> 6;
  float acca[32] = {}, accb[32] = {};

  for (int ph = 0; ph < 2; ++ph) {
    __syncthreads();
    #pragma unroll
    for (int i = 0; i < 12; ++i) {
      int id = i * 256 + t;
      int q = id & 15;
      int rid = id >> 4;
      int ch = rid / 12, r = rid - ch * 12;
      int gy = y0 - 2 + r;
      float4 v = make_float4(0.f, 0.f, 0.f, 0.f);
      if (gy >= 0 && gy < 64)
        v = *(const float4*)(src + (size_t)(ph * 16 + ch) * HW + (gy << 6) + (q << 2));
      *(float4*)&in_t[(ch * 12 + r) * 68 + 2 + (q << 2)] = v;
    }
    #pragma unroll
    for (int i = 0; i < 3; ++i) {
      int id = i * 256 + t;
      int side = id & 3;
      int rid = id >> 2;
      int col = (side < 2) ? side : 64 + side;
      in_t[rid * 68 + col] = 0.0f;
    }
    __syncthreads();
    for (int cl = 0; cl < 16; ++cl) {
      int ci = ph * 16 + cl;
      const float* bp = &in_t[(cl * 12) * 68 + 2 + x];
      const float* wv = &dww[ci * 25];
      float da = 0.f, db = 0.f;
      #pragma unroll
      for (int k = 0; k < 25; ++k) {
        int dy = k / 5, dx = (k % 5) - 2;
        float w = wv[k];
        da = fmaf(w, bp[(yl + dy) * 68 + dx], da);
        db = fmaf(w, bp[(yl + 4 + dy) * 68 + dx], db);
      }
      #pragma unroll
      for (int m = 0; m < 32; ++m) {
        float w = pww[m * 32 + ci];
        acca[m] = fmaf(w, da, acca[m]);
        accb[m] = fmaf(w, db, accb[m]);
      }
    }
  }
  float* dst = out + ((size_t)b * C + g * 32) * HW + y0 * 64;
  #pragma unroll
  for (int m = 0; m < 32; ++m) {
    dst[(size_t)m * HW + (yl << 6) + x]        = acca[m];
    dst[(size_t)m * HW + ((yl + 4) << 6) + x]  = accb[m];
  }
}

// Attention phase A: partial ctx = K^T [V|1] over a 128-n slice, atomicAdd to ctxbuf.
__global__ __launch_bounds__(256) void att_ctx(
    const float* __restrict__ kv, const float* __restrict__ kvs,
    float* __restrict__ ctxbuf)
{
  __shared__ float kvt[64][129];
  const int head  = blockIdx.x;
  const int b     = blockIdx.y;
  const int slice = blockIdx.z & 31;
  const int z     = blockIdx.z >> 5;
  const int tid   = threadIdx.x;

  const float* kvsrc = (head < 8)
      ? kv  + ((size_t)b * 1024 + z * 512 + head * 64) * HW
      : kvs + ((size_t)b * 1024 + z * 512 + (head - 8) * 64) * HW;
  const int n0 = slice * 128;

  #pragma unroll
  for (int l = 0; l < 8; ++l) {
    int fid = tid + l * 256;
    int ch = fid >> 5;
    int nc = (fid & 31) << 2;
    float4 v = *(const float4*)(kvsrc + (size_t)ch * HW + n0 + nc);
    if (ch < 32) {
      v.x = fmaxf(v.x, 0.0f); v.y = fmaxf(v.y, 0.0f);
      v.z = fmaxf(v.z, 0.0f); v.w = fmaxf(v.w, 0.0f);
    }
    kvt[ch][nc] = v.x; kvt[ch][nc + 1] = v.y;
    kvt[ch][nc + 2] = v.z; kvt[ch][nc + 3] = v.w;
  }
  __syncthreads();

  const int td = tid & 15, te = tid >> 4;
  const int d0 = td * 2, e0 = te * 2;
  float a00 = 0, a01 = 0, a10 = 0, a11 = 0, c0 = 0, c1 = 0;
  #pragma unroll 8
  for (int nn = 0; nn < 128; ++nn) {
    float k0 = kvt[d0][nn], k1 = kvt[d0 + 1][nn];
    float v0 = kvt[32 + e0][nn], v1 = kvt[32 + e0 + 1][nn];
    a00 = fmaf(k0, v0, a00); a01 = fmaf(k0, v1, a01);
    a10 = fmaf(k1, v0, a10); a11 = fmaf(k1, v1, a11);
    c0 += k0; c1 += k1;
  }
  float* cp = ctxbuf + (size_t)(((z * 4 + b) * 16) + head) * 1056;
  atomic_add_f32(&cp[(d0 + 0) * 33 + e0 + 0], a00);
  atomic_add_f32(&cp[(d0 + 0) * 33 + e0 + 1], a01);
  atomic_add_f32(&cp[(d0 + 1) * 33 + e0 + 0], a10);
  atomic_add_f32(&cp[(d0 + 1) * 33 + e0 + 1], a11);
  if (te == 0) {
    atomic_add_f32(&cp[(d0 + 0) * 33 + 32], c0);
    atomic_add_f32(&cp[(d0 + 1) * 33 + 32], c1);
  }
}

// Attention phase B.
__global__ __launch_bounds__(256) void att_apply(
    const float* __restrict__ ctxbuf,
    const float* __restrict__ q0, const float* __restrict__ q0s,
    const float* __restrict__ q1, const float* __restrict__ q1s,
    float* __restrict__ outbase, size_t outstride)
{
  __shared__ float ctx[1056];
  const int head = blockIdx.x;
  const int b    = blockIdx.y;
  const int tile = blockIdx.z & 15;
  const int z    = blockIdx.z >> 4;
  const int tid  = threadIdx.x;

  const float* cp = ctxbuf + (size_t)(((z * 4 + b) * 16) + head) * 1056;
  for (int i = tid; i < 1056; i += 256) ctx[i] = cp[i];
  __syncthreads();

  const float* qb = (z == 0) ? (head < 8 ? q0 : q0s) : (head < 8 ? q1 : q1s);
  const float* qsrc = qb + ((size_t)b * 256 + (head & 7) * 32) * HW;
  float* outp = outbase + (size_t)z * outstride + ((size_t)b * 512 + head * 32) * HW;

  const int n = tile * 256 + tid;
  float qv[32];
  #pragma unroll
  for (int d = 0; d < 32; ++d)
    qv[d] = fmaxf(qsrc[(size_t)d * HW + n], 0.0f);
  float den = 1e-15f;
  #pragma unroll
  for (int d = 0; d < 32; ++d)
    den = fmaf(qv[d], ctx[d * 33 + 32], den);
  float rden = 1.0f / den;
  for (int e = 0; e < 32; ++e) {
    float s = 0.0f;
    #pragma unroll
    for (int d = 0; d < 32; ++d)
      s = fmaf(qv[d], ctx[d * 33 + e], s);
    outp[(size_t)e * HW + n] = s * rden;
  }
}

extern "C" void kernel_launch(void* const* d_in, const int* in_sizes, int n_in,
                              void* d_out, int out_size, void* d_ws, size_t ws_size,
                              hipStream_t stream) {
  (void)in_sizes; (void)n_in; (void)out_size; (void)ws_size;
  const float* rgb         = (const float*)d_in[0];
  const float* t           = (const float*)d_in[1];
  const float* m1_inv_w    = (const float*)d_in[2];
  const float* m1_inv_g    = (const float*)d_in[3];
  const float* m1_inv_b    = (const float*)d_in[4];
  const float* m1_dw_w     = (const float*)d_in[5];
  const float* m1_dw_g     = (const float*)d_in[6];
  const float* m1_dw_b     = (const float*)d_in[7];
  const float* m1_pw_w     = (const float*)d_in[8];
  const float* m1_pw_g     = (const float*)d_in[9];
  const float* m1_pw_b     = (const float*)d_in[10];
  const float* kv_w        = (const float*)d_in[11];
  const float* qrgb_w      = (const float*)d_in[12];
  const float* qt_w        = (const float*)d_in[13];
  const float* agg_kv_dw   = (const float*)d_in[14];
  const float* agg_kv_pw   = (const float*)d_in[15];
  const float* agg_t_dw    = (const float*)d_in[16];
  const float* agg_t_pw    = (const float*)d_in[17];
  const float* agg_rgb_dw  = (const float*)d_in[18];
  const float* agg_rgb_pw  = (const float*)d_in[19];
  const float* proj_w      = (const float*)d_in[20];
  const float* m2_inv_w    = (const float*)d_in[21];
  const float* m2_inv_bias = (const float*)d_in[22];
  const float* m2_dw_w     = (const float*)d_in[23];
  const float* m2_dw_bias  = (const float*)d_in[24];
  const float* m2_pw_w     = (const float*)d_in[25];
  const float* m2_pw_g     = (const float*)d_in[26];
  const float* m2_pw_b     = (const float*)d_in[27];
  float* outp = (float*)d_out;

  const size_t S = (size_t)4 * 256 * HW;   // one (B,256,64,64) fp32 tensor
  float* ws   = (float*)d_ws;
  float* bufA = ws;            // S
  float* bufB = ws + S;        // S
  float* bufE = ws + 2 * S;    // S (qt_s)
  float* bufF = ws + 3 * S;    // S (qrgb_s)
  float* KV   = ws + 4 * S;    // 4S (m1 partials; kv; later out1|out2)
  float* C4   = ws + 8 * S;    // 4S (qt/qrgb/proj/m2_pw partials; ctxbuf; m2_inv out)
  float* D4   = ws + 12 * S;   // 4S (kv_s; later m2_dw out)

  dim3 blk(256);
  const int RG = 4096;   // reduce grid: S/4 float4 / 256

  // m1 stem: split-K=4 GEMMs, partials in KV, reduce w/ fused epilogue
  gemm1x1_bigsplit<<<dim3(32, 2, 16), blk, 0, stream>>>(rgb, t, m1_inv_w, KV, 512, 256, 256, 128);
  reduce4_epi<<<dim3(RG), blk, 0, stream>>>((float4*)KV, (float4*)bufA, m1_inv_g, m1_inv_b, 2);
  dwconv3<<<dim3(1024), blk, 0, stream>>>(bufA, m1_dw_w, bufB, m1_dw_g, m1_dw_b, 255, 2);
  gemm1x1_bigsplit<<<dim3(32, 2, 16), blk, 0, stream>>>(bufB, bufB, m1_pw_w, KV, 256, 256, 256, 64);
  reduce4_epi<<<dim3(RG), blk, 0, stream>>>((float4*)KV, (float4*)bufA, m1_pw_g, m1_pw_b, 1);   // rgbt -> A

  // projections: kv fused big (1024 blocks); qt/qrgb split via C4
  gemm1x1_big<<<dim3(32, 8, 4), blk, 0, stream>>>(bufA, bufA, kv_w, KV, nullptr, nullptr, 256, 256, 1024, 0);  // kv
  gemm1x1_bigsplit<<<dim3(32, 2, 16), blk, 0, stream>>>(t, t, qt_w, C4, 256, 256, 256, 64);
  reduce4_epi<<<dim3(RG), blk, 0, stream>>>((float4*)C4, (float4*)bufB, nullptr, nullptr, 0);   // q_t -> B
  gemm1x1_bigsplit<<<dim3(32, 2, 16), blk, 0, stream>>>(rgb, rgb, qrgb_w, C4, 256, 256, 256, 64);
  reduce4_epi<<<dim3(RG), blk, 0, stream>>>((float4*)C4, (float4*)bufA, nullptr, nullptr, 0);   // q_rgb -> A

  // fused multi-scale aggregation (dw5x5 + grouped 1x1)
  agg_fused<<<dim3(32, 4, 8), blk, 0, stream>>>(KV,  agg_kv_dw,  agg_kv_pw,  D4,  1024);  // kv_s -> D4
  agg_fused<<<dim3(8, 4, 8),  blk, 0, stream>>>(bufB, agg_t_dw,  agg_t_pw,  bufE, 256);   // qt_s -> E
  agg_fused<<<dim3(8, 4, 8),  blk, 0, stream>>>(bufA, agg_rgb_dw, agg_rgb_pw, bufF, 256); // qrgb_s -> F

  // attention (ctxbuf at head of C4)
  zero_buf4<<<dim3(132), blk, 0, stream>>>((float4*)C4, 128 * 264);
  att_ctx<<<dim3(16, 4, 64), blk, 0, stream>>>(KV, D4, C4);
  att_apply<<<dim3(16, 4, 32), blk, 0, stream>>>(C4, bufB, bufE, bufA, bufF, KV, 2 * S);

  // proj: split-K=4 (in = out1|out2 in KV), partials in C4
  gemm1x1_bigsplit<<<dim3(32, 2, 16), blk, 0, stream>>>(KV, KV + 2 * S, proj_w, C4, 1024, 512, 256, 256);
  reduce4_epi<<<dim3(RG), blk, 0, stream>>>((float4*)C4, (float4*)bufB, nullptr, nullptr, 0);   // proj -> B
  // m2 tail
  gemm1x1_big<<<dim3(32, 8, 4), blk, 0, stream>>>(bufB, bufB, m2_inv_w, C4, nullptr, m2_inv_bias, 256, 256, 1024, 3);
  dwconv3<<<dim3(4096), blk, 0, stream>>>(C4, m2_dw_w, D4, nullptr, m2_dw_bias, 1023, 3);
  gemm1x1_bigsplit<<<dim3(32, 2, 16), blk, 0, stream>>>(D4, D4, m2_pw_w, C4, 1024, 1024, 256, 256);
  reduce4_epi<<<dim3(RG), blk, 0, stream>>>((float4*)C4, (float4*)outp, m2_pw_g, m2_pw_b, 1);
}

// Round 10
// 889.945 us; speedup vs baseline: 1.8878x; 1.2560x over previous
//
#include <hip/hip_runtime.h>

#define HW 4096
#define S_E ((size_t)4 * 256 * 4096)   // elems in one (B,256,64,64) tensor

using f16   = _Float16;
using f16x8 = __attribute__((ext_vector_type(8))) _Float16;
using f32x4 = __attribute__((ext_vector_type(4))) float;

__device__ __forceinline__ float hswish(float x) {
  float r = fminf(fmaxf(x + 3.0f, 0.0f), 6.0f);
  return x * r * (1.0f / 6.0f);
}

__device__ __forceinline__ void atomic_add_f32(float* p, float v) {
  __hip_atomic_fetch_add(p, v, __ATOMIC_RELAXED, __HIP_MEMORY_SCOPE_AGENT);
}

__global__ __launch_bounds__(256) void zero_buf4(float4* __restrict__ p, int n4) {
  int i = blockIdx.x * 256 + threadIdx.x;
  if (i < n4) p[i] = make_float4(0.f, 0.f, 0.f, 0.f);
}

// fp32 -> f16 hi/lo planes (x = hi + lo, ~22 significand bits)
__global__ __launch_bounds__(256) void cvt_planes(
    const float* __restrict__ in, f16* __restrict__ hi, f16* __restrict__ lo, int n4)
{
  int i = blockIdx.x * 256 + threadIdx.x;
  if (i >= n4) return;
  float4 v = ((const float4*)in)[i];
  const float* f = &v.x;
  unsigned int hw[2], lw[2];
  #pragma unroll
  for (int j = 0; j < 2; ++j) {
    f16 h0 = (f16)f[2 * j], h1 = (f16)f[2 * j + 1];
    f16 l0 = (f16)(f[2 * j] - (float)h0), l1 = (f16)(f[2 * j + 1] - (float)h1);
    hw[j] = (unsigned int)__builtin_bit_cast(unsigned short, h0) |
            ((unsigned int)__builtin_bit_cast(unsigned short, h1) << 16);
    lw[j] = (unsigned int)__builtin_bit_cast(unsigned short, l0) |
            ((unsigned int)__builtin_bit_cast(unsigned short, l1) << 16);
  }
  *(uint2*)(hi + 4 * (size_t)i) = make_uint2(hw[0], hw[1]);
  *(uint2*)(lo + 4 * (size_t)i) = make_uint2(lw[0], lw[1]);
}

// f16x3 split MFMA 1x1-conv GEMM. Block: 256 thr / 4 waves; tile co128 x p64.
// Wave (wc,wp): co 64 x p 32 = 4m x 2n MFMA tiles, 3 MFMA terms each.
// W (A-operand) read from global (k-contiguous b128 frags); X (B) staged in LDS
// [p][k] (stride 36 f16) via pack-transpose. out: fp32 (out!=null) or f16 planes.
// epi: 0 none, 1 g*x+b, 2 hswish(g*x+b), 3 hswish(x+b). Grid (64, CO/128, 4).
__global__ __launch_bounds__(256) void gemm_mfma(
    const f16* __restrict__ xhi0, const f16* __restrict__ xlo0,
    const f16* __restrict__ xhi1, const f16* __restrict__ xlo1,
    const f16* __restrict__ whi, const f16* __restrict__ wlo,
    float* __restrict__ out, f16* __restrict__ ohi, f16* __restrict__ olo,
    const float* __restrict__ scale, const float* __restrict__ bias,
    int K, int k0, int CO, int epi)
{
  __shared__ f16 Bh[64 * 36];
  __shared__ f16 Bl[64 * 36];
  const int p0  = blockIdx.x * 64;
  const int co0 = blockIdx.y * 128;
  const int b   = blockIdx.z;
  const int tid = threadIdx.x;
  const int lane = tid & 63;
  const int wave = tid >> 6;
  const int wc = wave & 1, wp = wave >> 1;
  const int k1 = K - k0;

  // staging: 128 threads per plane; each stages 2k x 8p f16
  const int tt    = tid & 127;
  const int kbase = (tt >> 3) * 2;
  const int poct  = (tt & 7) * 8;
  const f16* x0 = (tid < 128) ? xhi0 : xlo0;
  const f16* x1 = (tid < 128) ? xhi1 : xlo1;
  f16* Bp = (tid < 128) ? Bh : Bl;

  const int q  = lane >> 4;   // 0..3
  const int ln = lane & 15;

  f32x4 acc[4][2];
  #pragma unroll
  for (int im = 0; im < 4; ++im)
    #pragma unroll
    for (int in = 0; in < 2; ++in)
      acc[im][in] = (f32x4){0.f, 0.f, 0.f, 0.f};

  uint4 g0, g1;
  {
    int kg = kbase;
    const f16* x = (kg < k0) ? x0 + ((size_t)b * k0 + kg) * HW
                             : x1 + ((size_t)b * k1 + (kg - k0)) * HW;
    g0 = *(const uint4*)(x + p0 + poct);
    g1 = *(const uint4*)(x + HW + p0 + poct);
  }

  for (int kt = 0; kt < K; kt += 32) {
    {
      const unsigned short* u0 = (const unsigned short*)&g0;
      const unsigned short* u1 = (const unsigned short*)&g1;
      #pragma unroll
      for (int i = 0; i < 8; ++i) {
        unsigned int d = (unsigned int)u0[i] | ((unsigned int)u1[i] << 16);
        *(unsigned int*)(Bp + (poct + i) * 36 + kbase) = d;
      }
    }
    __syncthreads();
    if (kt + 32 < K) {
      int kg = kt + 32 + kbase;
      const f16* x = (kg < k0) ? x0 + ((size_t)b * k0 + kg) * HW
                               : x1 + ((size_t)b * k1 + (kg - k0)) * HW;
      g0 = *(const uint4*)(x + p0 + poct);
      g1 = *(const uint4*)(x + HW + p0 + poct);
    }
    // B frags (shared across the 4 m-tiles)
    f16x8 bh[2], bl[2];
    #pragma unroll
    for (int in = 0; in < 2; ++in) {
      const f16* fp = &Bh[(wp * 32 + in * 16 + ln) * 36 + q * 8];
      const f16* gp = &Bl[(wp * 32 + in * 16 + ln) * 36 + q * 8];
      ((uint2*)&bh[in])[0] = *(const uint2*)fp;
      ((uint2*)&bh[in])[1] = *(const uint2*)(fp + 4);
      ((uint2*)&bl[in])[0] = *(const uint2*)gp;
      ((uint2*)&bl[in])[1] = *(const uint2*)(gp + 4);
    }
    #pragma unroll
    for (int im = 0; im < 4; ++im) {
      size_t wofs = (size_t)(co0 + wc * 64 + im * 16 + ln) * K + kt + q * 8;
      f16x8 ah = *(const f16x8*)(whi + wofs);
      f16x8 al = *(const f16x8*)(wlo + wofs);
      #pragma unroll
      for (int in = 0; in < 2; ++in) {
        acc[im][in] = __builtin_amdgcn_mfma_f32_16x16x32_f16(ah, bh[in], acc[im][in], 0, 0, 0);
        acc[im][in] = __builtin_amdgcn_mfma_f32_16x16x32_f16(ah, bl[in], acc[im][in], 0, 0, 0);
        acc[im][in] = __builtin_amdgcn_mfma_f32_16x16x32_f16(al, bh[in], acc[im][in], 0, 0, 0);
      }
    }
    __syncthreads();
  }

  #pragma unroll
  for (int im = 0; im < 4; ++im) {
    #pragma unroll
    for (int in = 0; in < 2; ++in) {
      int p = p0 + wp * 32 + in * 16 + ln;
      #pragma unroll
      for (int r = 0; r < 4; ++r) {
        int co = co0 + wc * 64 + im * 16 + q * 4 + r;
        float v = acc[im][in][r];
        if (epi == 1)      v = v * scale[co] + bias[co];
        else if (epi == 2) v = hswish(v * scale[co] + bias[co]);
        else if (epi == 3) v = hswish(v + bias[co]);
        size_t idx = ((size_t)b * CO + co) * HW + p;
        if (out) out[idx] = v;
        else {
          f16 h = (f16)v;
          ohi[idx] = h;
          olo[idx] = (f16)(v - (float)h);
        }
      }
    }
  }
}

// LDS-tiled depthwise 3x3, pad 1. One block per (b,c). pmode 1 -> f16 planes out.
// epi: 2 hswish(scale*x+bias), 3 hswish(x+bias)
__global__ __launch_bounds__(256) void dwconv3(
    const float* __restrict__ in, const float* __restrict__ w,
    float* __restrict__ out, f16* __restrict__ ohi, f16* __restrict__ olo,
    const float* __restrict__ scale, const float* __restrict__ bias,
    int Cmask, int epi, int pmode)
{
  __shared__ float tl[66 * 66];
  const int bc = blockIdx.x;
  const int c  = bc & Cmask;
  const float* src = in + (size_t)bc * HW;
  const int t = threadIdx.x;
  for (int i = t; i < 66 * 66; i += 256) {
    int r = i / 66, cc = i - r * 66;
    int gy = r - 1, gx = cc - 1;
    float v = 0.0f;
    if (gy >= 0 && gy < 64 && gx >= 0 && gx < 64) v = src[(gy << 6) + gx];
    tl[i] = v;
  }
  const float* wp = w + c * 9;
  float w00 = wp[0], w01 = wp[1], w02 = wp[2];
  float w10 = wp[3], w11 = wp[4], w12 = wp[5];
  float w20 = wp[6], w21 = wp[7], w22 = wp[8];
  float g = (epi == 2) ? scale[c] : 1.0f;
  float bb = bias[c];
  __syncthreads();
  #pragma unroll 4
  for (int j = 0; j < 16; ++j) {
    int p = j * 256 + t;
    int y = p >> 6, x = p & 63;
    const float* bp = &tl[y * 66 + x];
    float s;
    s = w00 * bp[0]        + w01 * bp[1]        + w02 * bp[2];
    s = fmaf(w10, bp[66],    fmaf(w11, bp[67],    fmaf(w12, bp[68],  s)));
    s = fmaf(w20, bp[132],   fmaf(w21, bp[133],   fmaf(w22, bp[134], s)));
    float v = (epi == 2) ? hswish(s * g + bb) : hswish(s + bb);
    size_t idx = (size_t)bc * HW + p;
    if (pmode) {
      f16 h = (f16)v;
      ohi[idx] = h;
      olo[idx] = (f16)(v - (float)h);
    } else {
      out[idx] = v;
    }
  }
}

// Fused dw5x5(pad2) + grouped 1x1 (32->32 per group).
__global__ __launch_bounds__(256) void agg_fused(
    const float* __restrict__ in, const float* __restrict__ dw,
    const float* __restrict__ pw, float* __restrict__ out, int C)
{
  __shared__ float in_t[16 * 12 * 68];
  __shared__ float dww[32 * 25];
  __shared__ float pww[32 * 32];
  const int g = blockIdx.x, b = blockIdx.y, tile = blockIdx.z;
  const int t = threadIdx.x;
  const int y0 = tile * 8;
  const float* src = in + ((size_t)b * C + g * 32) * HW;

  for (int i = t; i < 800; i += 256)  dww[i] = dw[(size_t)g * 800 + i];
  for (int i = t; i < 1024; i += 256) pww[i] = pw[(size_t)g * 1024 + i];

  const int x = t & 63, yl = t >> 6;
  float acca[32] = {}, accb[32] = {};

  for (int ph = 0; ph < 2; ++ph) {
    __syncthreads();
    #pragma unroll
    for (int i = 0; i < 12; ++i) {
      int id = i * 256 + t;
      int qq = id & 15;
      int rid = id >> 4;
      int ch = rid / 12, r = rid - ch * 12;
      int gy = y0 - 2 + r;
      float4 v = make_float4(0.f, 0.f, 0.f, 0.f);
      if (gy >= 0 && gy < 64)
        v = *(const float4*)(src + (size_t)(ph * 16 + ch) * HW + (gy << 6) + (qq << 2));
      *(float4*)&in_t[(ch * 12 + r) * 68 + 2 + (qq << 2)] = v;
    }
    #pragma unroll
    for (int i = 0; i < 3; ++i) {
      int id = i * 256 + t;
      int side = id & 3;
      int rid = id >> 2;
      int col = (side < 2) ? side : 64 + side;
      in_t[rid * 68 + col] = 0.0f;
    }
    __syncthreads();
    for (int cl = 0; cl < 16; ++cl) {
      int ci = ph * 16 + cl;
      const float* bp = &in_t[(cl * 12) * 68 + 2 + x];
      const float* wv = &dww[ci * 25];
      float da = 0.f, db = 0.f;
      #pragma unroll
      for (int k = 0; k < 25; ++k) {
        int dy = k / 5, dx = (k % 5) - 2;
        float w = wv[k];
        da = fmaf(w, bp[(yl + dy) * 68 + dx], da);
        db = fmaf(w, bp[(yl + 4 + dy) * 68 + dx], db);
      }
      #pragma unroll
      for (int m = 0; m < 32; ++m) {
        float w = pww[m * 32 + ci];
        acca[m] = fmaf(w, da, acca[m]);
        accb[m] = fmaf(w, db, accb[m]);
      }
    }
  }
  float* dst = out + ((size_t)b * C + g * 32) * HW + y0 * 64;
  #pragma unroll
  for (int m = 0; m < 32; ++m) {
    dst[(size_t)m * HW + (yl << 6) + x]        = acca[m];
    dst[(size_t)m * HW + ((yl + 4) << 6) + x]  = accb[m];
  }
}

// Attention phase A: partial ctx = K^T [V|1] over a 128-n slice, atomicAdd to ctxbuf.
__global__ __launch_bounds__(256) void att_ctx(
    const float* __restrict__ kv, const float* __restrict__ kvs,
    float* __restrict__ ctxbuf)
{
  __shared__ float kvt[64][129];
  const int head  = blockIdx.x;
  const int b     = blockIdx.y;
  const int slice = blockIdx.z & 31;
  const int z     = blockIdx.z >> 5;
  const int tid   = threadIdx.x;

  const float* kvsrc = (head < 8)
      ? kv  + ((size_t)b * 1024 + z * 512 + head * 64) * HW
      : kvs + ((size_t)b * 1024 + z * 512 + (head - 8) * 64) * HW;
  const int n0 = slice * 128;

  #pragma unroll
  for (int l = 0; l < 8; ++l) {
    int fid = tid + l * 256;
    int ch = fid >> 5;
    int nc = (fid & 31) << 2;
    float4 v = *(const float4*)(kvsrc + (size_t)ch * HW + n0 + nc);
    if (ch < 32) {
      v.x = fmaxf(v.x, 0.0f); v.y = fmaxf(v.y, 0.0f);
      v.z = fmaxf(v.z, 0.0f); v.w = fmaxf(v.w, 0.0f);
    }
    kvt[ch][nc] = v.x; kvt[ch][nc + 1] = v.y;
    kvt[ch][nc + 2] = v.z; kvt[ch][nc + 3] = v.w;
  }
  __syncthreads();

  const int td = tid & 15, te = tid >> 4;
  const int d0 = td * 2, e0 = te * 2;
  float a00 = 0, a01 = 0, a10 = 0, a11 = 0, c0 = 0, c1 = 0;
  #pragma unroll 8
  for (int nn = 0; nn < 128; ++nn) {
    float k0 = kvt[d0][nn], k1 = kvt[d0 + 1][nn];
    float v0 = kvt[32 + e0][nn], v1 = kvt[32 + e0 + 1][nn];
    a00 = fmaf(k0, v0, a00); a01 = fmaf(k0, v1, a01);
    a10 = fmaf(k1, v0, a10); a11 = fmaf(k1, v1, a11);
    c0 += k0; c1 += k1;
  }
  float* cp = ctxbuf + (size_t)(((z * 4 + b) * 16) + head) * 1056;
  atomic_add_f32(&cp[(d0 + 0) * 33 + e0 + 0], a00);
  atomic_add_f32(&cp[(d0 + 0) * 33 + e0 + 1], a01);
  atomic_add_f32(&cp[(d0 + 1) * 33 + e0 + 0], a10);
  atomic_add_f32(&cp[(d0 + 1) * 33 + e0 + 1], a11);
  if (te == 0) {
    atomic_add_f32(&cp[(d0 + 0) * 33 + 32], c0);
    atomic_add_f32(&cp[(d0 + 1) * 33 + 32], c1);
  }
}

// Attention phase B -> f16 planes out (feeds proj GEMM only).
// H layout: [out1hi(2S_E f16)][out1lo][out2hi][out2lo]
__global__ __launch_bounds__(256) void att_apply(
    const float* __restrict__ ctxbuf,
    const float* __restrict__ q0, const float* __restrict__ q0s,
    const float* __restrict__ q1, const float* __restrict__ q1s,
    f16* __restrict__ H)
{
  __shared__ float ctx[1056];
  const int head = blockIdx.x;
  const int b    = blockIdx.y;
  const int tile = blockIdx.z & 15;
  const int z    = blockIdx.z >> 4;
  const int tid  = threadIdx.x;

  const float* cp = ctxbuf + (size_t)(((z * 4 + b) * 16) + head) * 1056;
  for (int i = tid; i < 1056; i += 256) ctx[i] = cp[i];
  __syncthreads();

  const float* qb = (z == 0) ? (head < 8 ? q0 : q0s) : (head < 8 ? q1 : q1s);
  const float* qsrc = qb + ((size_t)b * 256 + (head & 7) * 32) * HW;
  f16* oh = H + (size_t)z * (4 * S_E);
  f16* ol = oh + 2 * S_E;

  const int n = tile * 256 + tid;
  float qv[32];
  #pragma unroll
  for (int d = 0; d < 32; ++d)
    qv[d] = fmaxf(qsrc[(size_t)d * HW + n], 0.0f);
  float den = 1e-15f;
  #pragma unroll
  for (int d = 0; d < 32; ++d)
    den = fmaf(qv[d], ctx[d * 33 + 32], den);
  float rden = 1.0f / den;
  for (int e = 0; e < 32; ++e) {
    float s = 0.0f;
    #pragma unroll
    for (int d = 0; d < 32; ++d)
      s = fmaf(qv[d], ctx[d * 33 + e], s);
    float v = s * rden;
    size_t idx = ((size_t)b * 512 + head * 32 + e) * HW + n;
    f16 h = (f16)v;
    oh[idx] = h;
    ol[idx] = (f16)(v - (float)h);
  }
}

extern "C" void kernel_launch(void* const* d_in, const int* in_sizes, int n_in,
                              void* d_out, int out_size, void* d_ws, size_t ws_size,
                              hipStream_t stream) {
  (void)in_sizes; (void)n_in; (void)out_size; (void)ws_size;
  const float* rgb         = (const float*)d_in[0];
  const float* t           = (const float*)d_in[1];
  const float* m1_inv_w    = (const float*)d_in[2];
  const float* m1_inv_g    = (const float*)d_in[3];
  const float* m1_inv_b    = (const float*)d_in[4];
  const float* m1_dw_w     = (const float*)d_in[5];
  const float* m1_dw_g     = (const float*)d_in[6];
  const float* m1_dw_b     = (const float*)d_in[7];
  const float* m1_pw_w     = (const float*)d_in[8];
  const float* m1_pw_g     = (const float*)d_in[9];
  const float* m1_pw_b     = (const float*)d_in[10];
  const float* kv_w        = (const float*)d_in[11];
  const float* qrgb_w      = (const float*)d_in[12];
  const float* qt_w        = (const float*)d_in[13];
  const float* agg_kv_dw   = (const float*)d_in[14];
  const float* agg_kv_pw   = (const float*)d_in[15];
  const float* agg_t_dw    = (const float*)d_in[16];
  const float* agg_t_pw    = (const float*)d_in[17];
  const float* agg_rgb_dw  = (const float*)d_in[18];
  const float* agg_rgb_pw  = (const float*)d_in[19];
  const float* proj_w      = (const float*)d_in[20];
  const float* m2_inv_w    = (const float*)d_in[21];
  const float* m2_inv_bias = (const float*)d_in[22];
  const float* m2_dw_w     = (const float*)d_in[23];
  const float* m2_dw_bias  = (const float*)d_in[24];
  const float* m2_pw_w     = (const float*)d_in[25];
  const float* m2_pw_g     = (const float*)d_in[26];
  const float* m2_pw_b     = (const float*)d_in[27];
  float* outp = (float*)d_out;

  const size_t S = S_E;              // float-units per S-slot
  float* ws = (float*)d_ws;
  // slots (float units):
  f16*   rgbH  = (f16*)(ws + 0 * S);            // rgb planes (hi, lo=+S_E)
  f16*   tH    = (f16*)(ws + 1 * S);            // t planes
  float* s2    = ws + 2 * S;                    // m1_inv out fp32 -> q_t fp32
  f16*   dw1H  = (f16*)(ws + 3 * S);            // m1_dw planes -> (reuse) qts fp32
  float* s3f   = ws + 3 * S;
  f16*   rgbtH = (f16*)(ws + 4 * S);            // rgbt planes -> qrgbs fp32
  float* s4f   = ws + 4 * S;
  float* s5    = ws + 5 * S;                    // q_rgb fp32
  float* KV    = ws + 6 * S;                    // kv fp32 (4S) -> att planes / m2_dw planes
  f16*   attH  = (f16*)(ws + 6 * S);
  float* KVS   = ws + 10 * S;                   // kv_s fp32 (4S) -> m2_inv out fp32
  float* CTX   = ws + 14 * S;                   // ctxbuf (135168 fl)
  float* WB    = ws + 14 * S + 150016;          // weight planes arena
  f16*   projH = (f16*)(ws + 15 * S);           // proj planes out

  // weight plane slots (f16-elem offsets into WB)
  f16* wb = (f16*)WB;
  f16* w_m1inv = wb;                 // 131072 elems
  f16* w_m1pw  = wb + 262144;        // 65536
  f16* w_kv    = wb + 393216;        // 262144
  f16* w_qt    = wb + 917504;        // 65536
  f16* w_qrgb  = wb + 1048576;       // 65536
  f16* w_proj  = wb + 1179648;       // 262144
  f16* w_m2inv = wb + 1703936;       // 262144
  f16* w_m2pw  = wb + 2228224;       // 262144

  dim3 blk(256);
  const int XN4 = (int)(S_E / 4);    // 1048576

  // input + weight plane conversions
  cvt_planes<<<dim3(4096), blk, 0, stream>>>(rgb, rgbH, rgbH + S_E, XN4);
  cvt_planes<<<dim3(4096), blk, 0, stream>>>(t,   tH,   tH   + S_E, XN4);
  cvt_planes<<<dim3(128), blk, 0, stream>>>(m1_inv_w, w_m1inv, w_m1inv + 131072, 32768);
  cvt_planes<<<dim3(64),  blk, 0, stream>>>(m1_pw_w,  w_m1pw,  w_m1pw  + 65536, 16384);
  cvt_planes<<<dim3(256), blk, 0, stream>>>(kv_w,     w_kv,    w_kv    + 262144, 65536);
  cvt_planes<<<dim3(64),  blk, 0, stream>>>(qt_w,     w_qt,    w_qt    + 65536, 16384);
  cvt_planes<<<dim3(64),  blk, 0, stream>>>(qrgb_w,   w_qrgb,  w_qrgb  + 65536, 16384);
  cvt_planes<<<dim3(256), blk, 0, stream>>>(proj_w,   w_proj,  w_proj  + 262144, 65536);
  cvt_planes<<<dim3(256), blk, 0, stream>>>(m2_inv_w, w_m2inv, w_m2inv + 262144, 65536);
  cvt_planes<<<dim3(256), blk, 0, stream>>>(m2_pw_w,  w_m2pw,  w_m2pw  + 262144, 65536);

  // m1 stem
  gemm_mfma<<<dim3(64, 2, 4), blk, 0, stream>>>(
      rgbH, rgbH + S_E, tH, tH + S_E, w_m1inv, w_m1inv + 131072,
      s2, nullptr, nullptr, m1_inv_g, m1_inv_b, 512, 256, 256, 2);
  dwconv3<<<dim3(1024), blk, 0, stream>>>(
      s2, m1_dw_w, nullptr, dw1H, dw1H + S_E, m1_dw_g, m1_dw_b, 255, 2, 1);
  gemm_mfma<<<dim3(64, 2, 4), blk, 0, stream>>>(
      dw1H, dw1H + S_E, dw1H, dw1H + S_E, w_m1pw, w_m1pw + 65536,
      nullptr, rgbtH, rgbtH + S_E, m1_pw_g, m1_pw_b, 256, 256, 256, 1);

  // projections
  gemm_mfma<<<dim3(64, 8, 4), blk, 0, stream>>>(
      rgbtH, rgbtH + S_E, rgbtH, rgbtH + S_E, w_kv, w_kv + 262144,
      KV, nullptr, nullptr, nullptr, nullptr, 256, 256, 1024, 0);
  gemm_mfma<<<dim3(64, 2, 4), blk, 0, stream>>>(
      tH, tH + S_E, tH, tH + S_E, w_qt, w_qt + 65536,
      s2, nullptr, nullptr, nullptr, nullptr, 256, 256, 256, 0);          // q_t -> s2
  gemm_mfma<<<dim3(64, 2, 4), blk, 0, stream>>>(
      rgbH, rgbH + S_E, rgbH, rgbH + S_E, w_qrgb, w_qrgb + 65536,
      s5, nullptr, nullptr, nullptr, nullptr, 256, 256, 256, 0);          // q_rgb -> s5

  // multi-scale aggregation
  agg_fused<<<dim3(32, 4, 8), blk, 0, stream>>>(KV, agg_kv_dw, agg_kv_pw, KVS, 1024); // kv_s
  agg_fused<<<dim3(8, 4, 8),  blk, 0, stream>>>(s2, agg_t_dw,  agg_t_pw,  s3f, 256);  // qt_s
  agg_fused<<<dim3(8, 4, 8),  blk, 0, stream>>>(s5, agg_rgb_dw, agg_rgb_pw, s4f, 256);// qrgb_s

  // attention
  zero_buf4<<<dim3(132), blk, 0, stream>>>((float4*)CTX, 128 * 264);
  att_ctx<<<dim3(16, 4, 64), blk, 0, stream>>>(KV, KVS, CTX);
  att_apply<<<dim3(16, 4, 32), blk, 0, stream>>>(CTX, s2, s3f, s5, s4f, attH);

  // proj + m2 tail
  gemm_mfma<<<dim3(64, 2, 4), blk, 0, stream>>>(
      attH, attH + 2 * S_E, attH + 4 * S_E, attH + 6 * S_E, w_proj, w_proj + 262144,
      nullptr, projH, projH + S_E, nullptr, nullptr, 1024, 512, 256, 0);
  gemm_mfma<<<dim3(64, 8, 4), blk, 0, stream>>>(
      projH, projH + S_E, projH, projH + S_E, w_m2inv, w_m2inv + 262144,
      KVS, nullptr, nullptr, nullptr, m2_inv_bias, 256, 256, 1024, 3);
  dwconv3<<<dim3(4096), blk, 0, stream>>>(
      KVS, m2_dw_w, nullptr, (f16*)(ws + 6 * S), (f16*)(ws + 8 * S),
      nullptr, m2_dw_bias, 1023, 3, 1);
  gemm_mfma<<<dim3(64, 2, 4), blk, 0, stream>>>(
      (f16*)(ws + 6 * S), (f16*)(ws + 8 * S), (f16*)(ws + 6 * S), (f16*)(ws + 8 * S),
      w_m2pw, w_m2pw + 262144,
      outp, nullptr, nullptr, m2_pw_g, m2_pw_b, 1024, 1024, 256, 1);
}

// Round 11
// 842.055 us; speedup vs baseline: 1.9951x; 1.0569x over previous
//
#include <hip/hip_runtime.h>

#define HW 4096
#define S_E ((size_t)4 * 256 * 4096)   // elems in one (B,256,64,64) tensor

using f16   = _Float16;
using f16x8 = __attribute__((ext_vector_type(8))) _Float16;
using f32x4 = __attribute__((ext_vector_type(4))) float;

__device__ __forceinline__ float hswish(float x) {
  float r = fminf(fmaxf(x + 3.0f, 0.0f), 6.0f);
  return x * r * (1.0f / 6.0f);
}

__device__ __forceinline__ void atomic_add_f32(float* p, float v) {
  __hip_atomic_fetch_add(p, v, __ATOMIC_RELAXED, __HIP_MEMORY_SCOPE_AGENT);
}

__global__ __launch_bounds__(256) void zero_buf4(float4* __restrict__ p, int n4) {
  int i = blockIdx.x * 256 + threadIdx.x;
  if (i < n4) p[i] = make_float4(0.f, 0.f, 0.f, 0.f);
}

// fp32 -> f16 hi/lo planes (x = hi + lo, ~22 significand bits)
__global__ __launch_bounds__(256) void cvt_planes(
    const float* __restrict__ in, f16* __restrict__ hi, f16* __restrict__ lo, int n4)
{
  int i = blockIdx.x * 256 + threadIdx.x;
  if (i >= n4) return;
  float4 v = ((const float4*)in)[i];
  const float* f = &v.x;
  unsigned int hw[2], lw[2];
  #pragma unroll
  for (int j = 0; j < 2; ++j) {
    f16 h0 = (f16)f[2 * j], h1 = (f16)f[2 * j + 1];
    f16 l0 = (f16)(f[2 * j] - (float)h0), l1 = (f16)(f[2 * j + 1] - (float)h1);
    hw[j] = (unsigned int)__builtin_bit_cast(unsigned short, h0) |
            ((unsigned int)__builtin_bit_cast(unsigned short, h1) << 16);
    lw[j] = (unsigned int)__builtin_bit_cast(unsigned short, l0) |
            ((unsigned int)__builtin_bit_cast(unsigned short, l1) << 16);
  }
  *(uint2*)(hi + 4 * (size_t)i) = make_uint2(hw[0], hw[1]);
  *(uint2*)(lo + 4 * (size_t)i) = make_uint2(lw[0], lw[1]);
}

// f16x3 split MFMA 1x1-conv GEMM (unchanged from R10; see R7 note: acc loops fully unrolled).
__global__ __launch_bounds__(256) void gemm_mfma(
    const f16* __restrict__ xhi0, const f16* __restrict__ xlo0,
    const f16* __restrict__ xhi1, const f16* __restrict__ xlo1,
    const f16* __restrict__ whi, const f16* __restrict__ wlo,
    float* __restrict__ out, f16* __restrict__ ohi, f16* __restrict__ olo,
    const float* __restrict__ scale, const float* __restrict__ bias,
    int K, int k0, int CO, int epi)
{
  __shared__ f16 Bh[64 * 36];
  __shared__ f16 Bl[64 * 36];
  const int p0  = blockIdx.x * 64;
  const int co0 = blockIdx.y * 128;
  const int b   = blockIdx.z;
  const int tid = threadIdx.x;
  const int lane = tid & 63;
  const int wave = tid >> 6;
  const int wc = wave & 1, wp = wave >> 1;
  const int k1 = K - k0;

  const int tt    = tid & 127;
  const int kbase = (tt >> 3) * 2;
  const int poct  = (tt & 7) * 8;
  const f16* x0 = (tid < 128) ? xhi0 : xlo0;
  const f16* x1 = (tid < 128) ? xhi1 : xlo1;
  f16* Bp = (tid < 128) ? Bh : Bl;

  const int q  = lane >> 4;
  const int ln = lane & 15;

  f32x4 acc[4][2];
  #pragma unroll
  for (int im = 0; im < 4; ++im)
    #pragma unroll
    for (int in = 0; in < 2; ++in)
      acc[im][in] = (f32x4){0.f, 0.f, 0.f, 0.f};

  uint4 g0, g1;
  {
    int kg = kbase;
    const f16* x = (kg < k0) ? x0 + ((size_t)b * k0 + kg) * HW
                             : x1 + ((size_t)b * k1 + (kg - k0)) * HW;
    g0 = *(const uint4*)(x + p0 + poct);
    g1 = *(const uint4*)(x + HW + p0 + poct);
  }

  for (int kt = 0; kt < K; kt += 32) {
    {
      const unsigned short* u0 = (const unsigned short*)&g0;
      const unsigned short* u1 = (const unsigned short*)&g1;
      #pragma unroll
      for (int i = 0; i < 8; ++i) {
        unsigned int d = (unsigned int)u0[i] | ((unsigned int)u1[i] << 16);
        *(unsigned int*)(Bp + (poct + i) * 36 + kbase) = d;
      }
    }
    __syncthreads();
    if (kt + 32 < K) {
      int kg = kt + 32 + kbase;
      const f16* x = (kg < k0) ? x0 + ((size_t)b * k0 + kg) * HW
                               : x1 + ((size_t)b * k1 + (kg - k0)) * HW;
      g0 = *(const uint4*)(x + p0 + poct);
      g1 = *(const uint4*)(x + HW + p0 + poct);
    }
    f16x8 bh[2], bl[2];
    #pragma unroll
    for (int in = 0; in < 2; ++in) {
      const f16* fp = &Bh[(wp * 32 + in * 16 + ln) * 36 + q * 8];
      const f16* gp = &Bl[(wp * 32 + in * 16 + ln) * 36 + q * 8];
      ((uint2*)&bh[in])[0] = *(const uint2*)fp;
      ((uint2*)&bh[in])[1] = *(const uint2*)(fp + 4);
      ((uint2*)&bl[in])[0] = *(const uint2*)gp;
      ((uint2*)&bl[in])[1] = *(const uint2*)(gp + 4);
    }
    #pragma unroll
    for (int im = 0; im < 4; ++im) {
      size_t wofs = (size_t)(co0 + wc * 64 + im * 16 + ln) * K + kt + q * 8;
      f16x8 ah = *(const f16x8*)(whi + wofs);
      f16x8 al = *(const f16x8*)(wlo + wofs);
      #pragma unroll
      for (int in = 0; in < 2; ++in) {
        acc[im][in] = __builtin_amdgcn_mfma_f32_16x16x32_f16(ah, bh[in], acc[im][in], 0, 0, 0);
        acc[im][in] = __builtin_amdgcn_mfma_f32_16x16x32_f16(ah, bl[in], acc[im][in], 0, 0, 0);
        acc[im][in] = __builtin_amdgcn_mfma_f32_16x16x32_f16(al, bh[in], acc[im][in], 0, 0, 0);
      }
    }
    __syncthreads();
  }

  #pragma unroll
  for (int im = 0; im < 4; ++im) {
    #pragma unroll
    for (int in = 0; in < 2; ++in) {
      int p = p0 + wp * 32 + in * 16 + ln;
      #pragma unroll
      for (int r = 0; r < 4; ++r) {
        int co = co0 + wc * 64 + im * 16 + q * 4 + r;
        float v = acc[im][in][r];
        if (epi == 1)      v = v * scale[co] + bias[co];
        else if (epi == 2) v = hswish(v * scale[co] + bias[co]);
        else if (epi == 3) v = hswish(v + bias[co]);
        size_t idx = ((size_t)b * CO + co) * HW + p;
        if (out) out[idx] = v;
        else {
          f16 h = (f16)v;
          ohi[idx] = h;
          olo[idx] = (f16)(v - (float)h);
        }
      }
    }
  }
}

// LDS-tiled depthwise 3x3, pad 1. One block per (b,c). pmode 1 -> f16 planes out.
__global__ __launch_bounds__(256) void dwconv3(
    const float* __restrict__ in, const float* __restrict__ w,
    float* __restrict__ out, f16* __restrict__ ohi, f16* __restrict__ olo,
    const float* __restrict__ scale, const float* __restrict__ bias,
    int Cmask, int epi, int pmode)
{
  __shared__ float tl[66 * 66];
  const int bc = blockIdx.x;
  const int c  = bc & Cmask;
  const float* src = in + (size_t)bc * HW;
  const int t = threadIdx.x;
  for (int i = t; i < 66 * 66; i += 256) {
    int r = i / 66, cc = i - r * 66;
    int gy = r - 1, gx = cc - 1;
    float v = 0.0f;
    if (gy >= 0 && gy < 64 && gx >= 0 && gx < 64) v = src[(gy << 6) + gx];
    tl[i] = v;
  }
  const float* wp = w + c * 9;
  float w00 = wp[0], w01 = wp[1], w02 = wp[2];
  float w10 = wp[3], w11 = wp[4], w12 = wp[5];
  float w20 = wp[6], w21 = wp[7], w22 = wp[8];
  float g = (epi == 2) ? scale[c] : 1.0f;
  float bb = bias[c];
  __syncthreads();
  #pragma unroll 4
  for (int j = 0; j < 16; ++j) {
    int p = j * 256 + t;
    int y = p >> 6, x = p & 63;
    const float* bp = &tl[y * 66 + x];
    float s;
    s = w00 * bp[0]        + w01 * bp[1]        + w02 * bp[2];
    s = fmaf(w10, bp[66],    fmaf(w11, bp[67],    fmaf(w12, bp[68],  s)));
    s = fmaf(w20, bp[132],   fmaf(w21, bp[133],   fmaf(w22, bp[134], s)));
    float v = (epi == 2) ? hswish(s * g + bb) : hswish(s + bb);
    size_t idx = (size_t)bc * HW + p;
    if (pmode) {
      f16 h = (f16)v;
      ohi[idx] = h;
      olo[idx] = (f16)(v - (float)h);
    } else {
      out[idx] = v;
    }
  }
}

// Fused dw5x5(pad2) + grouped 1x1 (32->32 per group).
__global__ __launch_bounds__(256) void agg_fused(
    const float* __restrict__ in, const float* __restrict__ dw,
    const float* __restrict__ pw, float* __restrict__ out, int C)
{
  __shared__ float in_t[16 * 12 * 68];
  __shared__ float dww[32 * 25];
  __shared__ float pww[32 * 32];
  const int g = blockIdx.x, b = blockIdx.y, tile = blockIdx.z;
  const int t = threadIdx.x;
  const int y0 = tile * 8;
  const float* src = in + ((size_t)b * C + g * 32) * HW;

  for (int i = t; i < 800; i += 256)  dww[i] = dw[(size_t)g * 800 + i];
  for (int i = t; i < 1024; i += 256) pww[i] = pw[(size_t)g * 1024 + i];

  const int x = t & 63, yl = t >> 6;
  float acca[32] = {}, accb[32] = {};

  for (int ph = 0; ph < 2; ++ph) {
    __syncthreads();
    #pragma unroll
    for (int i = 0; i < 12; ++i) {
      int id = i * 256 + t;
      int qq = id & 15;
      int rid = id >> 4;
      int ch = rid / 12, r = rid - ch * 12;
      int gy = y0 - 2 + r;
      float4 v = make_float4(0.f, 0.f, 0.f, 0.f);
      if (gy >= 0 && gy < 64)
        v = *(const float4*)(src + (size_t)(ph * 16 + ch) * HW + (gy << 6) + (qq << 2));
      *(float4*)&in_t[(ch * 12 + r) * 68 + 2 + (qq << 2)] = v;
    }
    #pragma unroll
    for (int i = 0; i < 3; ++i) {
      int id = i * 256 + t;
      int side = id & 3;
      int rid = id >> 2;
      int col = (side < 2) ? side : 64 + side;
      in_t[rid * 68 + col] = 0.0f;
    }
    __syncthreads();
    for (int cl = 0; cl < 16; ++cl) {
      int ci = ph * 16 + cl;
      const float* bp = &in_t[(cl * 12) * 68 + 2 + x];
      const float* wv = &dww[ci * 25];
      float da = 0.f, db = 0.f;
      #pragma unroll
      for (int k = 0; k < 25; ++k) {
        int dy = k / 5, dx = (k % 5) - 2;
        float w = wv[k];
        da = fmaf(w, bp[(yl + dy) * 68 + dx], da);
        db = fmaf(w, bp[(yl + 4 + dy) * 68 + dx], db);
      }
      #pragma unroll
      for (int m = 0; m < 32; ++m) {
        float w = pww[m * 32 + ci];
        acca[m] = fmaf(w, da, acca[m]);
        accb[m] = fmaf(w, db, accb[m]);
      }
    }
  }
  float* dst = out + ((size_t)b * C + g * 32) * HW + y0 * 64;
  #pragma unroll
  for (int m = 0; m < 32; ++m) {
    dst[(size_t)m * HW + (yl << 6) + x]        = acca[m];
    dst[(size_t)m * HW + ((yl + 4) << 6) + x]  = accb[m];
  }
}

// Attention phase A, v2: 4x4 register tile per lane, float4 along n, XOR-swizzled
// LDS tile (conflict-free b128 reads), per-block cross-wave reduction, then one
// atomicAdd per ctx cell. Grid (16 heads, 4 b, 2z*32 slices of 128n), 256 thr.
__global__ __launch_bounds__(256) void att_ctx(
    const float* __restrict__ kv, const float* __restrict__ kvs,
    float* __restrict__ ctxbuf)
{
  __shared__ float tile[64 * 128];   // [row][nblk^sw(row)*4], 32 KB
  __shared__ float red[4 * 1056];    // per-wave partials, 16.5 KB
  const int head  = blockIdx.x;
  const int b     = blockIdx.y;
  const int slice = blockIdx.z & 31;
  const int z     = blockIdx.z >> 5;
  const int tid   = threadIdx.x;
  const int lane  = tid & 63;
  const int wave  = tid >> 6;
  const int td = lane & 7, te = lane >> 3;

  const float* kvsrc = (head < 8)
      ? kv  + ((size_t)b * 1024 + z * 512 + head * 64) * HW
      : kvs + ((size_t)b * 1024 + z * 512 + (head - 8) * 64) * HW;
  const int n0 = slice * 128;

  // stage 64ch x 128n, swizzled: float4 block nb of row ch -> slot nb ^ ((ch>>2)&7)
  #pragma unroll
  for (int j = 0; j < 8; ++j) {
    int slot = j * 256 + tid;          // 2048 float4 slots
    int ch = slot >> 5;                // 32 blocks per row
    int nb = slot & 31;
    float4 v = *(const float4*)(kvsrc + (size_t)ch * HW + n0 + (nb << 2));
    if (ch < 32) {
      v.x = fmaxf(v.x, 0.0f); v.y = fmaxf(v.y, 0.0f);
      v.z = fmaxf(v.z, 0.0f); v.w = fmaxf(v.w, 0.0f);
    }
    int sw = nb ^ ((ch >> 2) & 7);
    *(float4*)&tile[ch * 128 + (sw << 2)] = v;
  }
  __syncthreads();

  // wave w handles n-blocks [w*8, w*8+8): 4x4 tile, float4 over n
  float acc[4][4] = {};
  float cs[4] = {};
  #pragma unroll
  for (int j = 0; j < 8; ++j) {
    int nblk = wave * 8 + j;
    float4 kr[4], vr[4];
    #pragma unroll
    for (int r = 0; r < 4; ++r) {
      int d = td * 4 + r;                       // (d>>2)&7 == td
      kr[r] = *(const float4*)&tile[d * 128 + ((nblk ^ td) << 2)];
      int e = 32 + te * 4 + r;                  // (e>>2)&7 == te
      vr[r] = *(const float4*)&tile[e * 128 + ((nblk ^ te) << 2)];
    }
    #pragma unroll
    for (int r = 0; r < 4; ++r) {
      const float* kp = &kr[r].x;
      cs[r] += kp[0] + kp[1] + kp[2] + kp[3];
      #pragma unroll
      for (int rp = 0; rp < 4; ++rp) {
        const float* vp = &vr[rp].x;
        acc[r][rp] = fmaf(kp[0], vp[0],
                     fmaf(kp[1], vp[1],
                     fmaf(kp[2], vp[2],
                     fmaf(kp[3], vp[3], acc[r][rp]))));
      }
    }
  }

  // per-wave partials -> LDS
  float* rw = &red[wave * 1056];
  #pragma unroll
  for (int r = 0; r < 4; ++r) {
    #pragma unroll
    for (int rp = 0; rp < 4; ++rp)
      rw[(td * 4 + r) * 33 + te * 4 + rp] = acc[r][rp];
    if (te == 0) rw[(td * 4 + r) * 33 + 32] = cs[r];
  }
  __syncthreads();

  // cross-wave reduce + one atomic per cell
  float* cp = ctxbuf + (size_t)(((z * 4 + b) * 16) + head) * 1056;
  for (int i = tid; i < 1056; i += 256) {
    float s = red[i] + red[1056 + i] + red[2112 + i] + red[3168 + i];
    atomic_add_f32(cp + i, s);
  }
}

// Attention phase B -> f16 planes out (feeds proj GEMM only).
__global__ __launch_bounds__(256) void att_apply(
    const float* __restrict__ ctxbuf,
    const float* __restrict__ q0, const float* __restrict__ q0s,
    const float* __restrict__ q1, const float* __restrict__ q1s,
    f16* __restrict__ H)
{
  __shared__ float ctx[1056];
  const int head = blockIdx.x;
  const int b    = blockIdx.y;
  const int tile = blockIdx.z & 15;
  const int z    = blockIdx.z >> 4;
  const int tid  = threadIdx.x;

  const float* cp = ctxbuf + (size_t)(((z * 4 + b) * 16) + head) * 1056;
  for (int i = tid; i < 1056; i += 256) ctx[i] = cp[i];
  __syncthreads();

  const float* qb = (z == 0) ? (head < 8 ? q0 : q0s) : (head < 8 ? q1 : q1s);
  const float* qsrc = qb + ((size_t)b * 256 + (head & 7) * 32) * HW;
  f16* oh = H + (size_t)z * (4 * S_E);
  f16* ol = oh + 2 * S_E;

  const int n = tile * 256 + tid;
  float qv[32];
  #pragma unroll
  for (int d = 0; d < 32; ++d)
    qv[d] = fmaxf(qsrc[(size_t)d * HW + n], 0.0f);
  float den = 1e-15f;
  #pragma unroll
  for (int d = 0; d < 32; ++d)
    den = fmaf(qv[d], ctx[d * 33 + 32], den);
  float rden = 1.0f / den;
  for (int e = 0; e < 32; ++e) {
    float s = 0.0f;
    #pragma unroll
    for (int d = 0; d < 32; ++d)
      s = fmaf(qv[d], ctx[d * 33 + e], s);
    float v = s * rden;
    size_t idx = ((size_t)b * 512 + head * 32 + e) * HW + n;
    f16 h = (f16)v;
    oh[idx] = h;
    ol[idx] = (f16)(v - (float)h);
  }
}

extern "C" void kernel_launch(void* const* d_in, const int* in_sizes, int n_in,
                              void* d_out, int out_size, void* d_ws, size_t ws_size,
                              hipStream_t stream) {
  (void)in_sizes; (void)n_in; (void)out_size; (void)ws_size;
  const float* rgb         = (const float*)d_in[0];
  const float* t           = (const float*)d_in[1];
  const float* m1_inv_w    = (const float*)d_in[2];
  const float* m1_inv_g    = (const float*)d_in[3];
  const float* m1_inv_b    = (const float*)d_in[4];
  const float* m1_dw_w     = (const float*)d_in[5];
  const float* m1_dw_g     = (const float*)d_in[6];
  const float* m1_dw_b     = (const float*)d_in[7];
  const float* m1_pw_w     = (const float*)d_in[8];
  const float* m1_pw_g     = (const float*)d_in[9];
  const float* m1_pw_b     = (const float*)d_in[10];
  const float* kv_w        = (const float*)d_in[11];
  const float* qrgb_w      = (const float*)d_in[12];
  const float* qt_w        = (const float*)d_in[13];
  const float* agg_kv_dw   = (const float*)d_in[14];
  const float* agg_kv_pw   = (const float*)d_in[15];
  const float* agg_t_dw    = (const float*)d_in[16];
  const float* agg_t_pw    = (const float*)d_in[17];
  const float* agg_rgb_dw  = (const float*)d_in[18];
  const float* agg_rgb_pw  = (const float*)d_in[19];
  const float* proj_w      = (const float*)d_in[20];
  const float* m2_inv_w    = (const float*)d_in[21];
  const float* m2_inv_bias = (const float*)d_in[22];
  const float* m2_dw_w     = (const float*)d_in[23];
  const float* m2_dw_bias  = (const float*)d_in[24];
  const float* m2_pw_w     = (const float*)d_in[25];
  const float* m2_pw_g     = (const float*)d_in[26];
  const float* m2_pw_b     = (const float*)d_in[27];
  float* outp = (float*)d_out;

  const size_t S = S_E;
  float* ws = (float*)d_ws;
  f16*   rgbH  = (f16*)(ws + 0 * S);
  f16*   tH    = (f16*)(ws + 1 * S);
  float* s2    = ws + 2 * S;
  f16*   dw1H  = (f16*)(ws + 3 * S);
  float* s3f   = ws + 3 * S;
  f16*   rgbtH = (f16*)(ws + 4 * S);
  float* s4f   = ws + 4 * S;
  float* s5    = ws + 5 * S;
  float* KV    = ws + 6 * S;
  f16*   attH  = (f16*)(ws + 6 * S);
  float* KVS   = ws + 10 * S;
  float* CTX   = ws + 14 * S;
  float* WB    = ws + 14 * S + 150016;
  f16*   projH = (f16*)(ws + 15 * S);

  f16* wb = (f16*)WB;
  f16* w_m1inv = wb;
  f16* w_m1pw  = wb + 262144;
  f16* w_kv    = wb + 393216;
  f16* w_qt    = wb + 917504;
  f16* w_qrgb  = wb + 1048576;
  f16* w_proj  = wb + 1179648;
  f16* w_m2inv = wb + 1703936;
  f16* w_m2pw  = wb + 2228224;

  dim3 blk(256);
  const int XN4 = (int)(S_E / 4);

  cvt_planes<<<dim3(4096), blk, 0, stream>>>(rgb, rgbH, rgbH + S_E, XN4);
  cvt_planes<<<dim3(4096), blk, 0, stream>>>(t,   tH,   tH   + S_E, XN4);
  cvt_planes<<<dim3(128), blk, 0, stream>>>(m1_inv_w, w_m1inv, w_m1inv + 131072, 32768);
  cvt_planes<<<dim3(64),  blk, 0, stream>>>(m1_pw_w,  w_m1pw,  w_m1pw  + 65536, 16384);
  cvt_planes<<<dim3(256), blk, 0, stream>>>(kv_w,     w_kv,    w_kv    + 262144, 65536);
  cvt_planes<<<dim3(64),  blk, 0, stream>>>(qt_w,     w_qt,    w_qt    + 65536, 16384);
  cvt_planes<<<dim3(64),  blk, 0, stream>>>(qrgb_w,   w_qrgb,  w_qrgb  + 65536, 16384);
  cvt_planes<<<dim3(256), blk, 0, stream>>>(proj_w,   w_proj,  w_proj  + 262144, 65536);
  cvt_planes<<<dim3(256), blk, 0, stream>>>(m2_inv_w, w_m2inv, w_m2inv + 262144, 65536);
  cvt_planes<<<dim3(256), blk, 0, stream>>>(m2_pw_w,  w_m2pw,  w_m2pw  + 262144, 65536);

  // m1 stem
  gemm_mfma<<<dim3(64, 2, 4), blk, 0, stream>>>(
      rgbH, rgbH + S_E, tH, tH + S_E, w_m1inv, w_m1inv + 131072,
      s2, nullptr, nullptr, m1_inv_g, m1_inv_b, 512, 256, 256, 2);
  dwconv3<<<dim3(1024), blk, 0, stream>>>(
      s2, m1_dw_w, nullptr, dw1H, dw1H + S_E, m1_dw_g, m1_dw_b, 255, 2, 1);
  gemm_mfma<<<dim3(64, 2, 4), blk, 0, stream>>>(
      dw1H, dw1H + S_E, dw1H, dw1H + S_E, w_m1pw, w_m1pw + 65536,
      nullptr, rgbtH, rgbtH + S_E, m1_pw_g, m1_pw_b, 256, 256, 256, 1);

  // projections
  gemm_mfma<<<dim3(64, 8, 4), blk, 0, stream>>>(
      rgbtH, rgbtH + S_E, rgbtH, rgbtH + S_E, w_kv, w_kv + 262144,
      KV, nullptr, nullptr, nullptr, nullptr, 256, 256, 1024, 0);
  gemm_mfma<<<dim3(64, 2, 4), blk, 0, stream>>>(
      tH, tH + S_E, tH, tH + S_E, w_qt, w_qt + 65536,
      s2, nullptr, nullptr, nullptr, nullptr, 256, 256, 256, 0);
  gemm_mfma<<<dim3(64, 2, 4), blk, 0, stream>>>(
      rgbH, rgbH + S_E, rgbH, rgbH + S_E, w_qrgb, w_qrgb + 65536,
      s5, nullptr, nullptr, nullptr, nullptr, 256, 256, 256, 0);

  // multi-scale aggregation
  agg_fused<<<dim3(32, 4, 8), blk, 0, stream>>>(KV, agg_kv_dw, agg_kv_pw, KVS, 1024);
  agg_fused<<<dim3(8, 4, 8),  blk, 0, stream>>>(s2, agg_t_dw,  agg_t_pw,  s3f, 256);
  agg_fused<<<dim3(8, 4, 8),  blk, 0, stream>>>(s5, agg_rgb_dw, agg_rgb_pw, s4f, 256);

  // attention
  zero_buf4<<<dim3(132), blk, 0, stream>>>((float4*)CTX, 128 * 264);
  att_ctx<<<dim3(16, 4, 64), blk, 0, stream>>>(KV, KVS, CTX);
  att_apply<<<dim3(16, 4, 32), blk, 0, stream>>>(CTX, s2, s3f, s5, s4f, attH);

  // proj + m2 tail
  gemm_mfma<<<dim3(64, 2, 4), blk, 0, stream>>>(
      attH, attH + 2 * S_E, attH + 4 * S_E, attH + 6 * S_E, w_proj, w_proj + 262144,
      nullptr, projH, projH + S_E, nullptr, nullptr, 1024, 512, 256, 0);
  gemm_mfma<<<dim3(64, 8, 4), blk, 0, stream>>>(
      projH, projH + S_E, projH, projH + S_E, w_m2inv, w_m2inv + 262144,
      KVS, nullptr, nullptr, nullptr, m2_inv_bias, 256, 256, 1024, 3);
  dwconv3<<<dim3(4096), blk, 0, stream>>>(
      KVS, m2_dw_w, nullptr, (f16*)(ws + 6 * S), (f16*)(ws + 8 * S),
      nullptr, m2_dw_bias, 1023, 3, 1);
  gemm_mfma<<<dim3(64, 2, 4), blk, 0, stream>>>(
      (f16*)(ws + 6 * S), (f16*)(ws + 8 * S), (f16*)(ws + 6 * S), (f16*)(ws + 8 * S),
      w_m2pw, w_m2pw + 262144,
      outp, nullptr, nullptr, m2_pw_g, m2_pw_b, 1024, 1024, 256, 1);
}